// Round 2
// baseline (328.243 us; speedup 1.0000x reference)
//
#include <hip/hip_runtime.h>
#include <stdint.h>

// ============================================================================
// MessagePassing collapse:
//   e2 = (3+a_vc)*base,  base = LN((scores*softmax_e(scores)) @ Wp_vc^T)
//   n2 = (1+a)^3 * features + (1-a)((1+a)^2+(1+a)+1) * nb,  a = ec_alpha
//   nb = LN((inc @ base) @ Wp_ec^T)  (LN positive-scale-invariant)
//   EC's MHA is dead code.
// R11: ALL GEMM main loops LDS-free (operand fragments loaded direct from
// L2-resident panels; no barriers in K-loops — kills the per-K-step
// vmcnt(0)+barrier drain that dominates small-tile 2-phase loops, per
// common-mistake #7 "don't stage what L2 fits"). Edge keeps its tiny
// PLinv-transform A-stage (B direct); node keeps only the As2 handoff
// (1 barrier). attn: +s_setprio around MFMA. Swizzles/epilogues = R10.
// ============================================================================

#define DEV static __device__ __forceinline__

typedef __attribute__((ext_vector_type(8))) short bf16x8;
typedef __attribute__((ext_vector_type(4))) float f32x4;

DEV uint16_t f2bf(float x){
  union{float f; uint32_t u;} v; v.f=x;
  uint32_t r = v.u + 0x7fffu + ((v.u>>16)&1u);
  return (uint16_t)(r>>16);
}
DEV float bf2f(uint16_t b){
  union{uint32_t u; float f;} v; v.u=((uint32_t)b)<<16; return v.f;
}

DEV uint32_t cvtpk_bf16(float lo, float hi){
  uint32_t d;
  asm("v_cvt_pk_bf16_f32 %0, %1, %2" : "=v"(d) : "v"(lo), "v"(hi));
  return d;
}

#if __has_builtin(__builtin_amdgcn_exp2f)
DEV float exp2fast(float x){ return __builtin_amdgcn_exp2f(x); }
#else
DEV float exp2fast(float x){ return __expf(x * 0.6931471805599453f); }
#endif

// ---------------------------------------------------------------------------
// merged prep: blocks [0,12288) = inc prep (f32 copy out + bf16 + bf16^T);
// blocks [12288,14720) = f32->bf16 casts of features + 4 weights.
// ---------------------------------------------------------------------------
__global__ __launch_bounds__(256)
void prep(const float* __restrict__ inc, float* __restrict__ out_inc,
          uint16_t* __restrict__ incb, uint16_t* __restrict__ incT,
          const float* __restrict__ feats, const float* __restrict__ win,
          const float* __restrict__ wout, const float* __restrict__ wpv,
          const float* __restrict__ wpe,
          uint16_t* __restrict__ xb, uint16_t* __restrict__ ow,
          uint16_t* __restrict__ oo, uint16_t* __restrict__ ov,
          uint16_t* __restrict__ oe){
  __shared__ float T[32][33];
  int bx = blockIdx.x;
  int tid = threadIdx.x;
  if (bx < 12288){
    int x = bx % 48;           // e tile
    int t = bx / 48;
    int y = t % 32;            // m tile
    int b = t / 32;            // batch
    int c0 = x*32, r0 = y*32;
    int tx = tid & 31, ty = tid >> 5;
    size_t base = (size_t)b*1024*1536;
#pragma unroll
    for (int j=0;j<4;++j){
      int r = r0 + ty + j*8;
      size_t idx = base + (size_t)r*1536 + c0 + tx;
      float v = inc[idx];
      T[ty+j*8][tx] = v;
      out_inc[idx] = v;
      incb[idx] = f2bf(v);
    }
    __syncthreads();
    size_t baseT = (size_t)b*1536*1024;
#pragma unroll
    for (int j=0;j<4;++j){
      int c = c0 + ty + j*8;
      incT[baseT + (size_t)c*1024 + r0 + tx] = f2bf(T[tx][ty+j*8]);
    }
  } else {
    int i = (bx - 12288)*256 + tid;   // i4 units, total 622592
    const float* src; uint16_t* dst; int j;
    if (i < 524288){ src=feats; dst=xb; j=i; }
    else {
      i -= 524288;
      if (i < 49152){ src=win; dst=ow; j=i; }
      else if (i < 65536){ src=wout; dst=oo; j=i-49152; }
      else if (i < 81920){ src=wpv; dst=ov; j=i-65536; }
      else { src=wpe; dst=oe; j=i-81920; }
    }
    float4 v = ((const float4*)src)[j];
    union { uint16_t u[4]; uint64_t q; } p;
    p.u[0]=f2bf(v.x); p.u[1]=f2bf(v.y); p.u[2]=f2bf(v.z); p.u[3]=f2bf(v.w);
    ((uint64_t*)dst)[j] = p.q;
  }
}

// ---------------------------------------------------------------------------
// LDS-free NT bf16 GEMM: C[M,N] = A[M,K]*B[N,K]^T (+bias). 256 thr = 2x2
// waves; M-tile 64, N-tile 128. Operand frags direct from global (B panels
// are L2-resident; A frags dedup via L1 across the 2 waves sharing them).
// No barriers at all. EPI: 0 = bf16 row-major; 1 = transposed bf16 store.
// ---------------------------------------------------------------------------
template<int EPI>
__global__ __launch_bounds__(256, 4)
void gemm_nt_d(const uint16_t* __restrict__ A, const uint16_t* __restrict__ B,
               uint16_t* __restrict__ Cb, const float* __restrict__ bias,
               int N, int K){
  const int tid = threadIdx.x;
  const int lane = tid & 63;
  const int w = tid >> 6;
  const int wm = w & 1, wn = w >> 1;
  const int r = lane & 15, q = lane >> 4;

  const uint16_t* apm[2];
  const uint16_t* bpn[4];
#pragma unroll
  for (int mt=0;mt<2;++mt)
    apm[mt] = A + (size_t)(blockIdx.x*64 + wm*32 + mt*16 + r)*K + q*8;
#pragma unroll
  for (int nt=0;nt<4;++nt)
    bpn[nt] = B + (size_t)(blockIdx.y*128 + wn*64 + nt*16 + r)*K + q*8;

  f32x4 acc[2][4];
#pragma unroll
  for (int i=0;i<2;++i)
#pragma unroll
    for (int j=0;j<4;++j) acc[i][j] = (f32x4){0.f,0.f,0.f,0.f};

#pragma unroll 4
  for (int kb=0; kb<K; kb+=32){
    bf16x8 af[2], bf[4];
#pragma unroll
    for (int mt=0;mt<2;++mt) af[mt] = *(const bf16x8*)(apm[mt] + kb);
#pragma unroll
    for (int nt=0;nt<4;++nt) bf[nt] = *(const bf16x8*)(bpn[nt] + kb);
#pragma unroll
    for (int mt=0;mt<2;++mt)
#pragma unroll
      for (int nt=0;nt<4;++nt)
        acc[mt][nt] = __builtin_amdgcn_mfma_f32_16x16x32_bf16(af[mt], bf[nt], acc[mt][nt], 0,0,0);
  }

  const int gm0 = blockIdx.x*64 + wm*32;
  const int gn0 = blockIdx.y*128 + wn*64;

  if constexpr (EPI == 1){
    // transposed bf16: out[b][gn][m'] with b = gm>>10, m' = gm&1023
#pragma unroll
    for (int mt=0;mt<2;++mt){
      int gmb = gm0 + mt*16 + q*4;
      size_t bb_ = (size_t)(gmb>>10)*(256*1024);
      int mm = gmb & 1023;
#pragma unroll
      for (int nt=0;nt<4;++nt){
        int gn = gn0 + nt*16 + r;
        float bv = bias ? bias[gn] : 0.f;
        union{uint16_t u[4]; uint64_t q64;} pk;
#pragma unroll
        for (int reg=0;reg<4;++reg) pk.u[reg] = f2bf(acc[mt][nt][reg] + bv);
        *(uint64_t*)(Cb + bb_ + (size_t)gn*1024 + mm) = pk.q64;
      }
    }
  } else {
#pragma unroll
    for (int mt=0;mt<2;++mt){
#pragma unroll
      for (int nt=0;nt<4;++nt){
        int gn = gn0 + nt*16 + r;
        float bv = bias ? bias[gn] : 0.f;
#pragma unroll
        for (int reg=0;reg<4;++reg){
          int gm = gm0 + mt*16 + q*4 + reg;   // C/D: col=lane&15, row=quad*4+reg
          Cb[(size_t)gm*N + gn] = f2bf(acc[mt][nt][reg] + bv);
        }
      }
    }
  }
}

// ---------------------------------------------------------------------------
// scores GEMM (LDS-free): C[e,d] = incT[e,:] . attnT[d,:]  (K=1024), tile
// 32e x 256d, 4 waves = 4 d-strips, no barriers. Writes VE = v*exp(v) bf16
// + per-block column exp-sums. Grid 384 = 8 batches * 48 e-tiles,
// XCD-swizzled (batch's 512KB B-panel on one XCD L2).
// ---------------------------------------------------------------------------
__global__ __launch_bounds__(256, 4)
void gemm_score(const uint16_t* __restrict__ A,   // INCT flat [8*1536][1024]
                const uint16_t* __restrict__ B,   // ATTNT [8][256][1024]
                float* __restrict__ part,         // [384][256]
                uint16_t* __restrict__ VE){       // [8*1536][256]
  const int tid = threadIdx.x;
  const int lane = tid & 63;
  const int w = tid >> 6;
  const int r = lane & 15, q = lane >> 4;
  const int bx = (blockIdx.x & 7)*48 + (blockIdx.x >> 3);   // bijective, 384=8*48
  const int batch = bx / 48;

  const uint16_t* apm[2];
  const uint16_t* bpn[4];
#pragma unroll
  for (int mt=0;mt<2;++mt)
    apm[mt] = A + (size_t)(bx*32 + mt*16 + r)*1024 + q*8;
#pragma unroll
  for (int nt=0;nt<4;++nt)
    bpn[nt] = B + (size_t)(batch*256 + w*64 + nt*16 + r)*1024 + q*8;

  f32x4 acc[2][4];
#pragma unroll
  for (int i=0;i<2;++i)
#pragma unroll
    for (int j=0;j<4;++j) acc[i][j] = (f32x4){0.f,0.f,0.f,0.f};

#pragma unroll 4
  for (int kb=0; kb<1024; kb+=32){
    bf16x8 af[2], bf[4];
#pragma unroll
    for (int mt=0;mt<2;++mt) af[mt] = *(const bf16x8*)(apm[mt] + kb);
#pragma unroll
    for (int nt=0;nt<4;++nt) bf[nt] = *(const bf16x8*)(bpn[nt] + kb);
#pragma unroll
    for (int mt=0;mt<2;++mt)
#pragma unroll
      for (int nt=0;nt<4;++nt)
        acc[mt][nt] = __builtin_amdgcn_mfma_f32_16x16x32_bf16(af[mt], bf[nt], acc[mt][nt], 0,0,0);
  }

#pragma unroll
  for (int nt=0;nt<4;++nt){
    int gn = w*64 + nt*16 + r;
    float s = 0.f;
#pragma unroll
    for (int mt=0;mt<2;++mt){
#pragma unroll
      for (int reg=0;reg<4;++reg){
        float v = acc[mt][nt][reg];
        float ev = __expf(v);
        s += ev;
        int row = mt*16 + q*4 + reg;
        VE[(size_t)(bx*32 + row)*256 + gn] = f2bf(v*ev);
      }
    }
    s += __shfl_xor(s, 16);
    s += __shfl_xor(s, 32);
    if (q == 0) part[(size_t)bx*256 + gn] = s;
  }
}

// ---------------------------------------------------------------------------
// Edge path: A = VE * (1/L) via tiny LDS stage (transform applied once per
// element); B = Wpv direct from L2 (128KB). LN + out_edge f32 + BASET bf16.
// Tile 32m x 256n, 256 thr. Grid 384, XCD-swizzled.
// ---------------------------------------------------------------------------
__global__ __launch_bounds__(256, 4)
void gemm_ln_edge(const uint16_t* __restrict__ SB, const uint16_t* __restrict__ B,
                  const float* __restrict__ part, const float* __restrict__ g,
                  const float* __restrict__ bb, const float* __restrict__ alpha,
                  float* __restrict__ out, uint16_t* __restrict__ baset){
  __shared__ short As[32*64];     // 4 KB
  __shared__ float lnS[4][32], lnQ[4][32];
  __shared__ float PLinv[256];
  const int tid = threadIdx.x;
  const int lane = tid & 63;
  const int w = tid >> 6;          // wave = wn strip 0..3
  const int r = lane & 15, q = lane >> 4;
  const int bx = (blockIdx.x & 7)*48 + (blockIdx.x >> 3);
  const int batch = bx / 48;

  // fold 48 PART partials -> 1/L
  {
    float s = 0.f;
#pragma unroll
    for (int i=0;i<48;++i) s += part[((size_t)batch*48 + i)*256 + tid];
    PLinv[tid] = 1.0f / s;
  }
  __syncthreads();

  f32x4 acc[2][4];
#pragma unroll
  for (int i=0;i<2;++i)
#pragma unroll
    for (int j=0;j<4;++j) acc[i][j] = (f32x4){0.f,0.f,0.f,0.f};

  const int srow = tid >> 3;   // 0..31
  const int sblk = tid & 7;

  const uint16_t* bpn[4];
#pragma unroll
  for (int nt=0;nt<4;++nt)
    bpn[nt] = B + (size_t)(w*64 + nt*16 + r)*256 + q*8;

  for (int kb = 0; kb < 256; kb += 64){
    // A stage: p = VE * (1/L)  (VGPR path, cvt_pk pack)
    {
      bf16x8 v = *(const bf16x8*)(SB + (size_t)(bx*32 + srow)*256 + kb + sblk*8);
      const float* Lp = &PLinv[kb + sblk*8];
      float xv[8];
#pragma unroll
      for (int j=0;j<8;++j) xv[j] = bf2f((uint16_t)v[j]) * Lp[j];
      union{uint32_t u[4]; bf16x8 v8;} pk;
      pk.u[0] = cvtpk_bf16(xv[0], xv[1]);
      pk.u[1] = cvtpk_bf16(xv[2], xv[3]);
      pk.u[2] = cvtpk_bf16(xv[4], xv[5]);
      pk.u[3] = cvtpk_bf16(xv[6], xv[7]);
      *(bf16x8*)&As[srow*64 + (sblk ^ (srow&7))*8] = pk.v8;
    }
    __syncthreads();
#pragma unroll
    for (int kc=0;kc<2;++kc){
      bf16x8 af[2], bf[4];
#pragma unroll
      for (int mt=0;mt<2;++mt){
        int m = mt*16 + r;
        af[mt] = *(const bf16x8*)&As[m*64 + ((kc*4 + q) ^ (m&7))*8];
      }
#pragma unroll
      for (int nt=0;nt<4;++nt)
        bf[nt] = *(const bf16x8*)(bpn[nt] + kb + kc*32);
#pragma unroll
      for (int mt=0;mt<2;++mt)
#pragma unroll
        for (int nt=0;nt<4;++nt)
          acc[mt][nt] = __builtin_amdgcn_mfma_f32_16x16x32_bf16(af[mt], bf[nt], acc[mt][nt], 0,0,0);
    }
    __syncthreads();
  }

  // cross-wave LN reduction
  float rs[2][4], rq[2][4];
#pragma unroll
  for (int mt=0;mt<2;++mt)
#pragma unroll
    for (int reg=0;reg<4;++reg){
      float s=0.f, s2=0.f;
#pragma unroll
      for (int nt=0;nt<4;++nt){
        float v = acc[mt][nt][reg];
        s += v; s2 += v*v;
      }
#pragma unroll
      for (int off=1; off<16; off<<=1){ s += __shfl_xor(s,off); s2 += __shfl_xor(s2,off); }
      rs[mt][reg]=s; rq[mt][reg]=s2;
    }
  if (r == 0){
#pragma unroll
    for (int mt=0;mt<2;++mt)
#pragma unroll
      for (int reg=0;reg<4;++reg){
        int row = mt*16 + q*4 + reg;
        lnS[w][row] = rs[mt][reg];
        lnQ[w][row] = rq[mt][reg];
      }
  }
  __syncthreads();

  const float c0 = 3.0f + alpha[0];
  float mu_[2][4], rstd_[2][4];
#pragma unroll
  for (int mt=0;mt<2;++mt)
#pragma unroll
    for (int reg=0;reg<4;++reg){
      int row = mt*16 + q*4 + reg;
      float S = lnS[0][row]+lnS[1][row]+lnS[2][row]+lnS[3][row];
      float Q = lnQ[0][row]+lnQ[1][row]+lnQ[2][row]+lnQ[3][row];
      float mu = S * (1.f/256.f);
      float var = fmaxf(Q*(1.f/256.f) - mu*mu, 0.f);
      mu_[mt][reg] = mu;
      rstd_[mt][reg] = rsqrtf(var + 1e-5f);
    }

  int e0 = (bx % 48) * 32;
#pragma unroll
  for (int mt=0;mt<2;++mt){
#pragma unroll
    for (int nt=0;nt<4;++nt){
      int gn = w*64 + nt*16 + r;
      float gv = g[gn], bv = bb[gn];
      union{uint16_t u[4]; uint64_t q64;} pk;
#pragma unroll
      for (int reg=0;reg<4;++reg){
        int row = mt*16 + q*4 + reg;
        size_t gm = (size_t)bx*32 + row;
        float o = ((acc[mt][nt][reg]-mu_[mt][reg])*rstd_[mt][reg]*gv + bv) * c0;
        pk.u[reg] = f2bf(o);
        out[gm*256 + gn] = o;
      }
      int ee = e0 + mt*16 + q*4;
      *(uint64_t*)(baset + ((size_t)batch*256 + gn)*1536 + ee) = pk.q64;
    }
  }
}

// ---------------------------------------------------------------------------
// Fused node path:
//   phase 1 (LDS-free): W0^T[d,m] = BASET[d,:] . INCB[m,:]  (K=1536, full
//            d=256 in-block, m-tile 32; BASET from XCD-local L2, INCB HBM)
//   handoff: W0^T -> As2 bf16 [m][d] swizzled (ONE barrier)
//   phase 2: C2^T[d',m] = WPEB[d',:] (direct L2) . As2[m,:]  (K=256)
//   epilogue: per-m LN over d' + blend with features.
// Grid 256 = 8 batches * 32 m-tiles, XCD-swizzled.
// ---------------------------------------------------------------------------
__global__ __launch_bounds__(256, 3)
void gemm_node_fused(const uint16_t* __restrict__ inc,    // INCB [8][1024][1536]
                     const uint16_t* __restrict__ baset,  // [8][256][1536]
                     const uint16_t* __restrict__ wpe,    // [256][256]
                     const float* __restrict__ g, const float* __restrict__ bb,
                     const float* __restrict__ alpha,
                     const float* __restrict__ feats, float* __restrict__ out){
  __shared__ short As2[32*256];   // 16KB: W0 bf16, swizzled
  __shared__ float lnSQ[256];     // [0..127]=S, [128..255]=Q
  const int tid = threadIdx.x;
  const int lane = tid & 63;
  const int w = tid >> 6;
  const int r = lane & 15, q = lane >> 4;
  const int bx = (blockIdx.x & 7)*32 + (blockIdx.x >> 3);  // bijective, 256=8*32
  const int batch = bx >> 5;
  const int mt0 = (bx & 31) * 32;

  const uint16_t* apm[4];
  const uint16_t* bpn[2];
#pragma unroll
  for (int mt=0;mt<4;++mt)
    apm[mt] = baset + (size_t)(batch*256 + w*64 + mt*16 + r)*1536 + q*8;
#pragma unroll
  for (int nt=0;nt<2;++nt)
    bpn[nt] = inc + (size_t)(batch*1024 + mt0 + nt*16 + r)*1536 + q*8;

  f32x4 acc1[4][2];
#pragma unroll
  for (int i=0;i<4;++i)
#pragma unroll
    for (int j=0;j<2;++j) acc1[i][j] = (f32x4){0.f,0.f,0.f,0.f};

  // ---- phase 1: K=1536 over e, no LDS, no barriers ----
#pragma unroll 4
  for (int kb = 0; kb < 1536; kb += 32){
    bf16x8 af[4], bf[2];
#pragma unroll
    for (int mt=0;mt<4;++mt) af[mt] = *(const bf16x8*)(apm[mt] + kb);
#pragma unroll
    for (int nt=0;nt<2;++nt) bf[nt] = *(const bf16x8*)(bpn[nt] + kb);
#pragma unroll
    for (int mt=0;mt<4;++mt)
#pragma unroll
      for (int nt=0;nt<2;++nt)
        acc1[mt][nt] = __builtin_amdgcn_mfma_f32_16x16x32_bf16(af[mt], bf[nt], acc1[mt][nt], 0,0,0);
  }

  // ---- W0^T -> As2[m][d] bf16, 16B-unit XOR swizzle (j ^ (m&7)) ----
  // acc1[mt][nt][reg] = W0^T[d][m], d = w*64+mt*16+q*4+reg, m = nt*16+r.
#pragma unroll
  for (int mt=0;mt<4;++mt){
    int j = w*8 + mt*2 + (q>>1);
#pragma unroll
    for (int nt=0;nt<2;++nt){
      int m = nt*16 + r;
      union{uint16_t u[4]; uint64_t q64;} pk;
#pragma unroll
      for (int reg=0;reg<4;++reg) pk.u[reg] = f2bf(acc1[mt][nt][reg]);
      *(uint64_t*)((char*)As2 + m*512 + ((j ^ (m&7))<<4) + ((q&1)<<3)) = pk.q64;
    }
  }
  __syncthreads();

  // ---- phase 2: K=256 over d, A = WPEB direct, B = As2 LDS ----
  f32x4 acc2[4][2];
#pragma unroll
  for (int i=0;i<4;++i)
#pragma unroll
    for (int j=0;j<2;++j) acc2[i][j] = (f32x4){0.f,0.f,0.f,0.f};

  const uint16_t* wpm[4];
#pragma unroll
  for (int mt=0;mt<4;++mt)
    wpm[mt] = wpe + (size_t)(w*64 + mt*16 + r)*256 + q*8;

#pragma unroll
  for (int kb = 0; kb < 256; kb += 32){
    bf16x8 af[4], bf[2];
#pragma unroll
    for (int mt=0;mt<4;++mt) af[mt] = *(const bf16x8*)(wpm[mt] + kb);
#pragma unroll
    for (int nt=0;nt<2;++nt){
      int m = nt*16 + r;
      int jr = (kb>>3) + q;
      bf[nt] = *(const bf16x8*)((char*)As2 + m*512 + ((jr ^ (m&7))<<4));
    }
#pragma unroll
    for (int mt=0;mt<4;++mt)
#pragma unroll
      for (int nt=0;nt<2;++nt)
        acc2[mt][nt] = __builtin_amdgcn_mfma_f32_16x16x32_bf16(af[mt], bf[nt], acc2[mt][nt], 0,0,0);
  }

  // ---- LN over d' (per column m), cross-wave via LDS ----
  float* lnS = lnSQ;              // [4][32]
  float* lnQ = lnSQ + 128;        // [4][32]
  float s_[2], q_[2];
#pragma unroll
  for (int nt=0;nt<2;++nt){
    float s=0.f, s2=0.f;
#pragma unroll
    for (int mt=0;mt<4;++mt)
#pragma unroll
      for (int reg=0;reg<4;++reg){
        float v = acc2[mt][nt][reg];
        s += v; s2 += v*v;
      }
    s += __shfl_xor(s,16); s2 += __shfl_xor(s2,16);
    s += __shfl_xor(s,32); s2 += __shfl_xor(s2,32);
    s_[nt]=s; q_[nt]=s2;
  }
  __syncthreads();   // As2 reads done before lnSQ aliasing writes? (separate buf — kept for ordering clarity)
  if (q == 0){
#pragma unroll
    for (int nt=0;nt<2;++nt){
      lnS[w*32 + nt*16 + r] = s_[nt];
      lnQ[w*32 + nt*16 + r] = q_[nt];
    }
  }
  __syncthreads();

  const float a = alpha[0];
  const float ap1 = 1.f + a;
  const float cn = (1.f - a)*(ap1*ap1 + ap1 + 1.f);
  const float cf = ap1*ap1*ap1;

  float mu_[2], rstd_[2];
#pragma unroll
  for (int nt=0;nt<2;++nt){
    int col = nt*16 + r;
    float S = lnS[col] + lnS[32+col] + lnS[64+col] + lnS[96+col];
    float Q = lnQ[col] + lnQ[32+col] + lnQ[64+col] + lnQ[96+col];
    float mu = S * (1.f/256.f);
    float var = fmaxf(Q*(1.f/256.f) - mu*mu, 0.f);
    mu_[nt] = mu;
    rstd_[nt] = rsqrtf(var + 1e-5f);
  }

  // ---- epilogue: out[m][d'] = cf*feats + cn*LN ----
#pragma unroll
  for (int mt=0;mt<4;++mt){
    int dp0 = w*64 + mt*16 + q*4;
    float4 gv = *(const float4*)&g[dp0];
    float4 bv = *(const float4*)&bb[dp0];
#pragma unroll
    for (int nt=0;nt<2;++nt){
      int m = nt*16 + r;
      size_t gm = (size_t)batch*1024 + mt0 + m;
      float4 fv = *(const float4*)&feats[gm*256 + dp0];
      float4 ov;
      ov.x = cf*fv.x + cn*((acc2[mt][nt][0]-mu_[nt])*rstd_[nt]*gv.x + bv.x);
      ov.y = cf*fv.y + cn*((acc2[mt][nt][1]-mu_[nt])*rstd_[nt]*gv.y + bv.y);
      ov.z = cf*fv.z + cn*((acc2[mt][nt][2]-mu_[nt])*rstd_[nt]*gv.z + bv.z);
      ov.w = cf*fv.w + cn*((acc2[mt][nt][3]-mu_[nt])*rstd_[nt]*gv.w + bv.w);
      *(float4*)&out[gm*256 + dp0] = ov;
    }
  }
}

// ---------------------------------------------------------------------------
// Attention: S^T = K*Q^T (A/B frags interchangeable), packed b64 P-store,
// scalar l. 512 thr = 8 waves x 16 q-rows. grid 512 (1D, XCD-swizzled).
// Max-free softmax; exp2 direct; cvt_pk P-pack; setprio around MFMA (T5).
// ---------------------------------------------------------------------------
DEV void stage_K(short* Kl, const uint16_t* __restrict__ qkv, size_t rowbase,
                 int c, int h, int kr){
  const uint16_t* kp = qkv + ((rowbase + c*256 + kr)*768 + 256 + h*32);
  int sz = (kr&3) ^ ((kr>>2)&1);
#pragma unroll
  for (int lb=0; lb<4; ++lb){
    bf16x8 v = *(const bf16x8*)(kp + lb*8);
    *(bf16x8*)&Kl[kr*32 + ((lb ^ sz))*8] = v;
  }
}

DEV void stage_V(short* VT, const uint16_t* __restrict__ qkv, size_t rowbase,
                 int c, int h, int t){
  int kvp = (t>>1)*2;
  int dhh = (t&1)*16;
  const uint16_t* v0 = qkv + ((rowbase + c*256 + kvp)*768 + 512 + h*32 + dhh);
  const uint16_t* v1 = v0 + 768;
  bf16x8 a0 = *(const bf16x8*)(v0);
  bf16x8 a1 = *(const bf16x8*)(v0+8);
  bf16x8 b0 = *(const bf16x8*)(v1);
  bf16x8 b1 = *(const bf16x8*)(v1+8);
  int blkbase = kvp>>3, off = kvp&7;
#pragma unroll
  for (int i=0;i<8;++i){
    int dh = dhh + i;
    uint32_t pack = (uint32_t)(uint16_t)a0[i] | ((uint32_t)(uint16_t)b0[i]<<16);
    *(uint32_t*)&VT[dh*256 + ((blkbase ^ (dh&7))*8) + off] = pack;
  }
#pragma unroll
  for (int i=0;i<8;++i){
    int dh = dhh + 8 + i;
    uint32_t pack = (uint32_t)(uint16_t)a1[i] | ((uint32_t)(uint16_t)b1[i]<<16);
    *(uint32_t*)&VT[dh*256 + ((blkbase ^ (dh&7))*8) + off] = pack;
  }
}

__global__ __launch_bounds__(512)
void attn_fwd(const uint16_t* __restrict__ qkv, uint16_t* __restrict__ O){
  __shared__ short Kl[256*32];
  __shared__ short VT[32*256];
  __shared__ short Pl[8][16*36];
  const int tid = threadIdx.x, lane = tid&63, w = tid>>6;
  const int r = lane&15, q = lane>>4;
  const int logical = (blockIdx.x & 7)*64 + (blockIdx.x >> 3); // 512=8*64 bijective
  const int bh = logical >> 3, qc = logical & 7;
  const int b = bh>>3, h = bh&7;
  const int q0 = qc*128 + w*16;
  const size_t rowbase = (size_t)b*1024;

  bf16x8 aq;
  {
    // 1/sqrt(32) * log2(e): S_mfma = log2(e) * qk/sqrt(dh) -> p = exp2(S_mfma)
    const float qscale = 0.25505654380651023f;
    const uint16_t* p = qkv + ((rowbase + q0 + r)*768 + h*32 + q*8);
    bf16x8 t = *(const bf16x8*)p;
#pragma unroll
    for (int j=0;j<8;++j)
      t[j] = (short)f2bf(bf2f((uint16_t)t[j]) * qscale);
    aq = t;
  }

  f32x4 o[2];
  o[0]=(f32x4){0.f,0.f,0.f,0.f}; o[1]=(f32x4){0.f,0.f,0.f,0.f};
  float l = 0.f;

  for (int c=0;c<4;++c){
    __syncthreads();
    if (tid < 256) stage_K(Kl, qkv, rowbase, c, h, tid);
    else           stage_V(VT, qkv, rowbase, c, h, tid-256);
    __syncthreads();
    for (int s32=0; s32<8; ++s32){
#pragma unroll
      for (int t2=0;t2<2;++t2){
        int rn = s32*32 + t2*16 + r;
        int sz = (rn&3) ^ ((rn>>2)&1);
        bf16x8 bk = *(const bf16x8*)&Kl[rn*32 + ((q ^ sz))*8];
        f32x4 z = (f32x4){0.f,0.f,0.f,0.f};
        __builtin_amdgcn_s_setprio(1);
        f32x4 st = __builtin_amdgcn_mfma_f32_16x16x32_bf16(bk, aq, z, 0,0,0);
        __builtin_amdgcn_s_setprio(0);
        float p0 = exp2fast(st[0]);
        float p1 = exp2fast(st[1]);
        float p2 = exp2fast(st[2]);
        float p3 = exp2fast(st[3]);
        l += (p0+p1)+(p2+p3);
        union{uint32_t u[2]; uint64_t q64;} pk;
        pk.u[0] = cvtpk_bf16(p0, p1);
        pk.u[1] = cvtpk_bf16(p2, p3);
        *(uint64_t*)&Pl[w][r*36 + t2*16 + q*4] = pk.q64;
      }
      bf16x8 bv[2];
#pragma unroll
      for (int db=0;db<2;++db){
        int dh = db*16 + r;
        bv[db] = *(const bf16x8*)&VT[dh*256 + (((s32*4 + q) ^ (dh&7)))*8];
      }
      bf16x8 ap = *(const bf16x8*)&Pl[w][r*36 + q*8];
      __builtin_amdgcn_s_setprio(1);
#pragma unroll
      for (int db=0;db<2;++db)
        o[db] = __builtin_amdgcn_mfma_f32_16x16x32_bf16(ap, bv[db], o[db], 0,0,0);
      __builtin_amdgcn_s_setprio(0);
    }
  }

  l += __shfl_xor(l, 16);
  l += __shfl_xor(l, 32);
#pragma unroll
  for (int db=0;db<2;++db)
#pragma unroll
    for (int reg=0;reg<4;++reg){
      float li = __shfl(l, q*4 + reg);
      int qr = q0 + q*4 + reg;
      O[(rowbase + qr)*256 + h*32 + db*16 + r] = f2bf(o[db][reg] / li);
    }
}

// ===========================================================================
extern "C" void kernel_launch(void* const* d_in, const int* in_sizes, int n_in,
                              void* d_out, int out_size, void* d_ws, size_t ws_size,
                              hipStream_t stream){
  const float* features = (const float*)d_in[0];
  const float* inc      = (const float*)d_in[1];
  const float* vc_Win   = (const float*)d_in[2];
  const float* vc_bin   = (const float*)d_in[3];
  const float* vc_Wout  = (const float*)d_in[4];
  const float* vc_bout  = (const float*)d_in[5];
  const float* vc_Wproj = (const float*)d_in[6];
  const float* vc_ln_g  = (const float*)d_in[7];
  const float* vc_ln_b  = (const float*)d_in[8];
  const float* vc_alpha = (const float*)d_in[9];
  const float* ec_Wproj = (const float*)d_in[14];
  const float* ec_ln_g  = (const float*)d_in[15];
  const float* ec_ln_b  = (const float*)d_in[16];
  const float* ec_alpha = (const float*)d_in[17];

  float* out = (float*)d_out;
  float* out_node = out;                 // [8,1024,256]
  float* out_edge = out + 2097152;       // [8,1536,256]
  float* out_inc  = out + 5242880;       // [8,1024,1536]

  char* ws = (char*)d_ws;
  uint16_t* XB     = (uint16_t*)(ws + 0);          // 4,194,304 (dead after qkv)
  float*    PART   = (float*)   (ws + 0);          // alias: 393,216 (384*256*4)
  uint16_t* WINB   = (uint16_t*)(ws + 4194304);    // 393,216
  uint16_t* WOUTB  = (uint16_t*)(ws + 4587520);    // 131,072
  uint16_t* WPVB   = (uint16_t*)(ws + 4718592);    // 131,072
  uint16_t* WPEB   = (uint16_t*)(ws + 4849664);    // 131,072
  uint16_t* INCB   = (uint16_t*)(ws + 4988928);    // 25,165,824
  uint16_t* INCT   = (uint16_t*)(ws + 30154752);   // 25,165,824
  uint16_t* QKVB   = (uint16_t*)(ws + 55320576);   // 12,582,912
  uint16_t* SCORESB= (uint16_t*)(ws + 55320576);   // alias: QKVB dead after attn
  uint16_t* OB     = (uint16_t*)(ws + 67903488);   // 4,194,304
  uint16_t* ATTNT  = (uint16_t*)(ws + 72097792);   // 4,194,304
  uint16_t* BASET  = (uint16_t*)(ws + 82583552);   // 6,291,456 (~89 MB total)

  // prep: inc (f32 out + bf16 + bf16^T) and all f32->bf16 casts, one kernel
  prep<<<14720,256,0,stream>>>(inc, out_inc, INCB, INCT,
                               features, vc_Win, vc_Wout, vc_Wproj, ec_Wproj,
                               XB, WINB, WOUTB, WPVB, WPEB);

  // MHA(features): qkv -> attention -> out-proj (writes ATTNT transposed)
  gemm_nt_d<0><<<dim3(128,6,1),256,0,stream>>>(XB, WINB, QKVB, vc_bin, 768, 256);
  attn_fwd<<<512,512,0,stream>>>(QKVB, OB);
  gemm_nt_d<1><<<dim3(128,2,1),256,0,stream>>>(OB, WOUTB, ATTNT, vc_bout, 256, 256);

  // scores = inc^T @ attn: LDS-free 32x256 tile, writes VE=v*exp(v) bf16
  // + 48 exp-sum partials/batch
  gemm_score<<<384,256,0,stream>>>(INCT, ATTNT, PART, SCORESB);

  // edge path: PART->1/L, p=VE/L staged A, Wpv direct, GEMM, LN,
  // out_edge f32 + BASET bf16 transposed. 384 blocks.
  gemm_ln_edge<<<384,256,0,stream>>>(SCORESB, WPVB, PART, vc_ln_g, vc_ln_b,
                                     vc_alpha, out_edge, BASET);

  // node path: ONE kernel — W0 = inc@base (K=1536, LDS-free) -> As2 LDS ->
  // @Wpe^T (K=256) + fused LN/blend. 256 blocks.
  gemm_node_fused<<<256,256,0,stream>>>(INCB, BASET, WPEB, ec_ln_g, ec_ln_b,
                                        ec_alpha, features, out_node);
}

// Round 3
// 255.928 us; speedup vs baseline: 1.2826x; 1.2826x over previous
//
#include <hip/hip_runtime.h>
#include <stdint.h>

// ============================================================================
// MessagePassing collapse:
//   e2 = (3+a_vc)*base,  base = LN((scores*softmax_e(scores)) @ Wp_vc^T)
//   n2 = (1+a)^3 * features + (1-a)((1+a)^2+(1+a)+1) * nb,  a = ec_alpha
//   nb = LN((inc @ base) @ Wp_ec^T)  (LN positive-scale-invariant)
//   EC's MHA is dead code.
// R12: REVERT R11's LDS-free GEMMs (uncoalesced frag loads -> 16 txn/load,
// latency-bound: MfmaUtil 4.3/VALUBusy 2.4/Occ 10% on node). Back to R10's
// staged kernels. NEW: (1) prep split into prep_cast (XB+weights, runs
// before qkv) + inc-prep FUSED into the qkv launch (qkv blocks bx<384
// dispatch first; 12288 inc-prep blocks overlap the otherwise-idle CUs) —
// overlaps ~20us of qkv compute under memory-bound prep. (2) attn keeps
// exp2/cvt_pk and adds s_setprio around MFMA clusters (T5, +4-7% attn).
// ============================================================================

#define DEV static __device__ __forceinline__

typedef __attribute__((ext_vector_type(8))) short bf16x8;
typedef __attribute__((ext_vector_type(4))) float f32x4;

DEV uint16_t f2bf(float x){
  union{float f; uint32_t u;} v; v.f=x;
  uint32_t r = v.u + 0x7fffu + ((v.u>>16)&1u);
  return (uint16_t)(r>>16);
}
DEV float bf2f(uint16_t b){
  union{uint32_t u; float f;} v; v.u=((uint32_t)b)<<16; return v.f;
}

DEV uint32_t cvtpk_bf16(float lo, float hi){
  uint32_t d;
  asm("v_cvt_pk_bf16_f32 %0, %1, %2" : "=v"(d) : "v"(lo), "v"(hi));
  return d;
}

#if __has_builtin(__builtin_amdgcn_exp2f)
DEV float exp2fast(float x){ return __builtin_amdgcn_exp2f(x); }
#else
DEV float exp2fast(float x){ return __expf(x * 0.6931471805599453f); }
#endif

#if __has_builtin(__builtin_amdgcn_global_load_lds)
#define HAVE_GLL 1
#else
#define HAVE_GLL 0
#endif

DEV void load_lds16(const uint16_t* g, void* l){
#if HAVE_GLL
  __builtin_amdgcn_global_load_lds((const __attribute__((address_space(1))) uint32_t*)g,
                                   (__attribute__((address_space(3))) uint32_t*)l, 16, 0, 0);
#else
  *(bf16x8*)l = *(const bf16x8*)g;
#endif
}

// ---------------------------------------------------------------------------
// prep_cast: f32->bf16 casts of features + 4 weights (must precede qkv GEMM).
// 2432 blocks x 256 thr, 622592 i4-units.
// ---------------------------------------------------------------------------
__global__ __launch_bounds__(256)
void prep_cast(const float* __restrict__ feats, const float* __restrict__ win,
               const float* __restrict__ wout, const float* __restrict__ wpv,
               const float* __restrict__ wpe,
               uint16_t* __restrict__ xb, uint16_t* __restrict__ ow,
               uint16_t* __restrict__ oo, uint16_t* __restrict__ ov,
               uint16_t* __restrict__ oe){
  int i = blockIdx.x*256 + threadIdx.x;   // i4 units, total 622592
  const float* src; uint16_t* dst; int j;
  if (i < 524288){ src=feats; dst=xb; j=i; }
  else {
    i -= 524288;
    if (i < 49152){ src=win; dst=ow; j=i; }
    else if (i < 65536){ src=wout; dst=oo; j=i-49152; }
    else if (i < 81920){ src=wpv; dst=ov; j=i-65536; }
    else { src=wpe; dst=oe; j=i-81920; }
  }
  float4 v = ((const float4*)src)[j];
  union { uint16_t u[4]; uint64_t q; } p;
  p.u[0]=f2bf(v.x); p.u[1]=f2bf(v.y); p.u[2]=f2bf(v.z); p.u[3]=f2bf(v.w);
  ((uint64_t*)dst)[j] = p.q;
}

// ---------------------------------------------------------------------------
// Fused launch: blocks [0,384) = qkv GEMM (C[8192,768] = XB @ WINB^T + bin,
// R10's gemm_nt<4,64,0> body, dispatched FIRST); blocks [384,12672) =
// inc prep (f32 copy out + bf16 + bf16^T). The memory-bound prep fills the
// CUs the 384 compute blocks leave idle.
// ---------------------------------------------------------------------------
__global__ __launch_bounds__(256, 3)
void qkv_incprep(const float* __restrict__ inc, float* __restrict__ out_inc,
                 uint16_t* __restrict__ incb, uint16_t* __restrict__ incT,
                 const uint16_t* __restrict__ A, const uint16_t* __restrict__ B,
                 uint16_t* __restrict__ Cb, const float* __restrict__ bias){
  __shared__ union {
    struct { short As[128*64]; short Bs[128*64]; } g;   // 32 KB
    float T[32][33];                                    // 4.2 KB
  } sm;
  const int tid = threadIdx.x;
  const int bx = blockIdx.x;

  if (bx < 384){
    // ---- qkv GEMM: WM=4, BK=64, M=8192, N=768, K=256 ----
    const int lane = tid & 63;
    const int w = tid >> 6;
    const int wm = w & 1, wn = w >> 1;
    const int r = lane & 15, q = lane >> 4;
    const int mtile = bx & 63, ntile = bx >> 6;   // 64 x 6
    const uint16_t* Ab = A + (size_t)(mtile*128)*256;
    const uint16_t* Bb = B + (size_t)(ntile*128)*256;
    f32x4 acc[4][4];
#pragma unroll
    for (int i=0;i<4;++i)
#pragma unroll
      for (int j=0;j<4;++j) acc[i][j] = (f32x4){0.f,0.f,0.f,0.f};

    const int srow = tid >> 3;   // UPR=8
    const int sblk = tid & 7;

    for (int kb = 0; kb < 256; kb += 64){
#pragma unroll
      for (int i=0;i<4;++i){     // 128 A-rows / 32 per pass
        int row = srow + 32*i;
        int lblk = sblk ^ (row & 7);
        load_lds16(Ab + (size_t)row*256 + kb + lblk*8, (char*)sm.g.As + i*4096 + tid*16);
      }
#pragma unroll
      for (int i=0;i<4;++i){     // 128 B-rows
        int row = srow + 32*i;
        int lblk = sblk ^ (row & 7);
        load_lds16(Bb + (size_t)row*256 + kb + lblk*8, (char*)sm.g.Bs + i*4096 + tid*16);
      }
      __syncthreads();
#pragma unroll
      for (int kc=0;kc<2;++kc){
        bf16x8 af[4], bfr[4];
#pragma unroll
        for (int mt=0;mt<4;++mt){
          int m = wm*64 + mt*16 + r;
          af[mt] = *(const bf16x8*)&sm.g.As[m*64 + ((kc*4 + q) ^ (m&7))*8];
        }
#pragma unroll
        for (int nt=0;nt<4;++nt){
          int n = wn*64 + nt*16 + r;
          bfr[nt] = *(const bf16x8*)&sm.g.Bs[n*64 + ((kc*4 + q) ^ (n&7))*8];
        }
#pragma unroll
        for (int mt=0;mt<4;++mt)
#pragma unroll
          for (int nt=0;nt<4;++nt)
            acc[mt][nt] = __builtin_amdgcn_mfma_f32_16x16x32_bf16(af[mt], bfr[nt], acc[mt][nt], 0,0,0);
      }
      __syncthreads();
    }

    const int gm0 = mtile*128 + wm*64;
    const int gn0 = ntile*128 + wn*64;
#pragma unroll
    for (int mt=0;mt<4;++mt){
#pragma unroll
      for (int nt=0;nt<4;++nt){
        int gn = gn0 + nt*16 + r;
        float bv = bias[gn];
#pragma unroll
        for (int reg=0;reg<4;++reg){
          int gm = gm0 + mt*16 + q*4 + reg;   // C/D: col=lane&15, row=quad*4+reg
          Cb[(size_t)gm*768 + gn] = f2bf(acc[mt][nt][reg] + bv);
        }
      }
    }
  } else {
    // ---- inc prep: f32 copy out + bf16 + bf16^T ----
    int bxp = bx - 384;
    int x = bxp % 48;           // e tile
    int t = bxp / 48;
    int y = t % 32;             // m tile
    int b = t / 32;             // batch
    int c0 = x*32, r0 = y*32;
    int tx = tid & 31, ty = tid >> 5;
    size_t base = (size_t)b*1024*1536;
#pragma unroll
    for (int j=0;j<4;++j){
      int r = r0 + ty + j*8;
      size_t idx = base + (size_t)r*1536 + c0 + tx;
      float v = inc[idx];
      sm.T[ty+j*8][tx] = v;
      out_inc[idx] = v;
      incb[idx] = f2bf(v);
    }
    __syncthreads();
    size_t baseT = (size_t)b*1536*1024;
#pragma unroll
    for (int j=0;j<4;++j){
      int c = c0 + ty + j*8;
      incT[baseT + (size_t)c*1024 + r0 + tx] = f2bf(sm.T[tx][ty+j*8]);
    }
  }
}

// ---------------------------------------------------------------------------
// NT bf16 GEMM (R10, LDS-staged): C[M,N] = A[M,K]*B[N,K]^T (+bias).
// WM: rows/wave = WM*16, M-tile = WM*32. N-tile 128. 256 thr (2x2 waves).
// EPI: 0 = bf16 row-major; 1 = transposed bf16 store (per-batch [N][1024]).
// ---------------------------------------------------------------------------
template<int WM, int BK, int EPI>
__global__ __launch_bounds__(256, 3)
void gemm_nt(const uint16_t* __restrict__ A, const uint16_t* __restrict__ B,
             uint16_t* __restrict__ Cb, const float* __restrict__ bias,
             int M, int N, int K){
  constexpr int AROWS = WM*32;
  constexpr int UPR = BK/8;        // 16B units per row
  constexpr int RPP = 256/UPR;     // rows staged per pass
  __shared__ short As[AROWS*BK];
  __shared__ short Bs[128*BK];
  const int tid = threadIdx.x;
  const int lane = tid & 63;
  const int w = tid >> 6;
  const int wm = w & 1, wn = w >> 1;
  const int r = lane & 15, q = lane >> 4;
  const uint16_t* Ab = A + (size_t)(blockIdx.x*AROWS)*K;
  const uint16_t* Bb = B + (size_t)(blockIdx.y*128)*K;
  f32x4 acc[WM][4];
#pragma unroll
  for (int i=0;i<WM;++i)
#pragma unroll
    for (int j=0;j<4;++j) acc[i][j] = (f32x4){0.f,0.f,0.f,0.f};

  const int srow = tid / UPR;
  const int sblk = tid % UPR;

  for (int kb = 0; kb < K; kb += BK){
#pragma unroll
    for (int i=0;i<AROWS/RPP;++i){
      int row = srow + RPP*i;
      int lblk = sblk ^ (row & (UPR-1));
      load_lds16(Ab + (size_t)row*K + kb + lblk*8, (char*)As + i*4096 + tid*16);
    }
#pragma unroll
    for (int i=0;i<128/RPP;++i){
      int row = srow + RPP*i;
      int lblk = sblk ^ (row & (UPR-1));
      load_lds16(Bb + (size_t)row*K + kb + lblk*8, (char*)Bs + i*4096 + tid*16);
    }
    __syncthreads();
#pragma unroll
    for (int kc=0;kc<BK/32;++kc){
      bf16x8 af[WM], bfr[4];
#pragma unroll
      for (int mt=0;mt<WM;++mt){
        int m = wm*(WM*16) + mt*16 + r;
        af[mt] = *(const bf16x8*)&As[m*BK + ((kc*4 + q) ^ (m&(UPR-1)))*8];
      }
#pragma unroll
      for (int nt=0;nt<4;++nt){
        int n = wn*64 + nt*16 + r;
        bfr[nt] = *(const bf16x8*)&Bs[n*BK + ((kc*4 + q) ^ (n&(UPR-1)))*8];
      }
#pragma unroll
      for (int mt=0;mt<WM;++mt)
#pragma unroll
        for (int nt=0;nt<4;++nt)
          acc[mt][nt] = __builtin_amdgcn_mfma_f32_16x16x32_bf16(af[mt], bfr[nt], acc[mt][nt], 0,0,0);
    }
    __syncthreads();
  }

  const int gm0 = blockIdx.x*AROWS + wm*(WM*16);
  const int gn0 = blockIdx.y*128 + wn*64;

  if constexpr (EPI == 1){
    // transposed bf16: out[b][gn][m'] with b = gm>>10, m' = gm&1023
#pragma unroll
    for (int mt=0;mt<WM;++mt){
      int gmb = gm0 + mt*16 + q*4;           // 4 consecutive rows via reg
      size_t bb_ = (size_t)(gmb>>10)*(256*1024);
      int mm = gmb & 1023;
#pragma unroll
      for (int nt=0;nt<4;++nt){
        int gn = gn0 + nt*16 + r;
        float bv = bias ? bias[gn] : 0.f;
        union{uint16_t u[4]; uint64_t q64;} pk;
#pragma unroll
        for (int reg=0;reg<4;++reg) pk.u[reg] = f2bf(acc[mt][nt][reg] + bv);
        *(uint64_t*)(Cb + bb_ + (size_t)gn*1024 + mm) = pk.q64;
      }
    }
  } else {
#pragma unroll
    for (int mt=0;mt<WM;++mt){
#pragma unroll
      for (int nt=0;nt<4;++nt){
        int gn = gn0 + nt*16 + r;
        float bv = bias ? bias[gn] : 0.f;
#pragma unroll
        for (int reg=0;reg<4;++reg){
          int gm = gm0 + mt*16 + q*4 + reg;
          Cb[(size_t)gm*N + gn] = f2bf(acc[mt][nt][reg] + bv);
        }
      }
    }
  }
}

// ---------------------------------------------------------------------------
// scores GEMM (R10): C[e,d] = incT[e,:] . attnT[d,:]  (K=1024), tile 32e x
// 256d, 256 thr (4 waves = 4 d-strips). INCT read exactly ONCE (full-N tile).
// Writes VE = v*exp(v) bf16 + per-block column exp-sums. Grid 384 = 8
// batches * 48 e-tiles, XCD-swizzled.
// ---------------------------------------------------------------------------
__global__ __launch_bounds__(256, 4)
void gemm_score(const uint16_t* __restrict__ A,   // INCT flat [8*1536][1024]
                const uint16_t* __restrict__ B,   // ATTNT [8][256][1024]
                float* __restrict__ part,         // [384][256]
                uint16_t* __restrict__ VE){       // [8*1536][256]
  __shared__ short As[32*64];
  __shared__ short Bs[256*64];
  const int tid = threadIdx.x;
  const int lane = tid & 63;
  const int w = tid >> 6;
  const int r = lane & 15, q = lane >> 4;
  const int bx = (blockIdx.x & 7)*48 + (blockIdx.x >> 3);   // bijective, 384=8*48
  const int batch = bx / 48;
  const uint16_t* Ab = A + (size_t)bx*32*1024;
  const uint16_t* Bb = B + (size_t)batch*256*1024;

  f32x4 acc[2][4];
#pragma unroll
  for (int i=0;i<2;++i)
#pragma unroll
    for (int j=0;j<4;++j) acc[i][j] = (f32x4){0.f,0.f,0.f,0.f};

  const int srow = tid >> 3;   // 0..31
  const int sblk = tid & 7;

  for (int kb = 0; kb < 1024; kb += 64){
    { int lblk = sblk ^ (srow & 7);
      load_lds16(Ab + (size_t)srow*1024 + kb + lblk*8, (char*)As + tid*16); }
#pragma unroll
    for (int i=0;i<8;++i){
      int row = srow + 32*i;
      int lblk = sblk ^ (row & 7);
      load_lds16(Bb + (size_t)row*1024 + kb + lblk*8, (char*)Bs + i*4096 + tid*16);
    }
    __syncthreads();
#pragma unroll
    for (int kc=0;kc<2;++kc){
      bf16x8 af[2], bfr[4];
#pragma unroll
      for (int mt=0;mt<2;++mt){
        int m = mt*16 + r;
        af[mt] = *(const bf16x8*)&As[m*64 + ((kc*4 + q) ^ (m&7))*8];
      }
#pragma unroll
      for (int nt=0;nt<4;++nt){
        int n = w*64 + nt*16 + r;
        bfr[nt] = *(const bf16x8*)&Bs[n*64 + ((kc*4 + q) ^ (n&7))*8];
      }
#pragma unroll
      for (int mt=0;mt<2;++mt)
#pragma unroll
        for (int nt=0;nt<4;++nt)
          acc[mt][nt] = __builtin_amdgcn_mfma_f32_16x16x32_bf16(af[mt], bfr[nt], acc[mt][nt], 0,0,0);
    }
    __syncthreads();
  }

#pragma unroll
  for (int nt=0;nt<4;++nt){
    int gn = w*64 + nt*16 + r;
    float s = 0.f;
#pragma unroll
    for (int mt=0;mt<2;++mt){
#pragma unroll
      for (int reg=0;reg<4;++reg){
        float v = acc[mt][nt][reg];
        float ev = __expf(v);
        s += ev;
        int row = mt*16 + q*4 + reg;
        VE[(size_t)(bx*32 + row)*256 + gn] = f2bf(v*ev);
      }
    }
    s += __shfl_xor(s, 16);
    s += __shfl_xor(s, 32);
    if (q == 0) part[(size_t)bx*256 + gn] = s;
  }
}

// ---------------------------------------------------------------------------
// Edge path (R10): A = VE * (1/L) computed during staging; L folded from 48
// partials/batch. GEMM vs Wpv^T + LN. Tile 32m x 256n, BK=64, 256 thr.
// Grid 384, XCD-swizzled. Writes out_edge f32 + BASET bf16 [b][d][e].
// ---------------------------------------------------------------------------
__global__ __launch_bounds__(256, 4)
void gemm_ln_edge(const uint16_t* __restrict__ SB, const uint16_t* __restrict__ B,
                  const float* __restrict__ part, const float* __restrict__ g,
                  const float* __restrict__ bb, const float* __restrict__ alpha,
                  float* __restrict__ out, uint16_t* __restrict__ baset){
  __shared__ short As[32*64];     // 4 KB
  __shared__ short Bs[256*64];    // 32 KB
  __shared__ float lnS[4][32], lnQ[4][32];
  __shared__ float PLinv[256];
  const int tid = threadIdx.x;
  const int lane = tid & 63;
  const int w = tid >> 6;          // wave = wn strip 0..3
  const int r = lane & 15, q = lane >> 4;
  const int bx = (blockIdx.x & 7)*48 + (blockIdx.x >> 3);
  const int batch = bx / 48;

  // fold 48 PART partials -> 1/L
  {
    float s = 0.f;
#pragma unroll
    for (int i=0;i<48;++i) s += part[((size_t)batch*48 + i)*256 + tid];
    PLinv[tid] = 1.0f / s;
  }
  __syncthreads();

  f32x4 acc[2][4];
#pragma unroll
  for (int i=0;i<2;++i)
#pragma unroll
    for (int j=0;j<4;++j) acc[i][j] = (f32x4){0.f,0.f,0.f,0.f};

  const int srow = tid >> 3;   // 0..31
  const int sblk = tid & 7;

  for (int kb = 0; kb < 256; kb += 64){
    // A stage: p = VE * (1/L)  (VGPR path, cvt_pk pack)
    {
      bf16x8 v = *(const bf16x8*)(SB + (size_t)(bx*32 + srow)*256 + kb + sblk*8);
      const float* Lp = &PLinv[kb + sblk*8];
      float xv[8];
#pragma unroll
      for (int j=0;j<8;++j) xv[j] = bf2f((uint16_t)v[j]) * Lp[j];
      union{uint32_t u[4]; bf16x8 v8;} pk;
      pk.u[0] = cvtpk_bf16(xv[0], xv[1]);
      pk.u[1] = cvtpk_bf16(xv[2], xv[3]);
      pk.u[2] = cvtpk_bf16(xv[4], xv[5]);
      pk.u[3] = cvtpk_bf16(xv[6], xv[7]);
      *(bf16x8*)&As[srow*64 + (sblk ^ (srow&7))*8] = pk.v8;
    }
#pragma unroll
    for (int i=0;i<8;++i){
      int row = srow + 32*i;
      int lblk = sblk ^ (row & 7);
      load_lds16(B + (size_t)row*256 + kb + lblk*8, (char*)Bs + i*4096 + tid*16);
    }
    __syncthreads();
#pragma unroll
    for (int kc=0;kc<2;++kc){
      bf16x8 af[2], bfr[4];
#pragma unroll
      for (int mt=0;mt<2;++mt){
        int m = mt*16 + r;
        af[mt] = *(const bf16x8*)&As[m*64 + ((kc*4 + q) ^ (m&7))*8];
      }
#pragma unroll
      for (int nt=0;nt<4;++nt){
        int n = w*64 + nt*16 + r;
        bfr[nt] = *(const bf16x8*)&Bs[n*64 + ((kc*4 + q) ^ (n&7))*8];
      }
#pragma unroll
      for (int mt=0;mt<2;++mt)
#pragma unroll
        for (int nt=0;nt<4;++nt)
          acc[mt][nt] = __builtin_amdgcn_mfma_f32_16x16x32_bf16(af[mt], bfr[nt], acc[mt][nt], 0,0,0);
    }
    __syncthreads();
  }

  // cross-wave LN reduction
  float rs[2][4], rq[2][4];
#pragma unroll
  for (int mt=0;mt<2;++mt)
#pragma unroll
    for (int reg=0;reg<4;++reg){
      float s=0.f, s2=0.f;
#pragma unroll
      for (int nt=0;nt<4;++nt){
        float v = acc[mt][nt][reg];
        s += v; s2 += v*v;
      }
#pragma unroll
      for (int off=1; off<16; off<<=1){ s += __shfl_xor(s,off); s2 += __shfl_xor(s2,off); }
      rs[mt][reg]=s; rq[mt][reg]=s2;
    }
  if (r == 0){
#pragma unroll
    for (int mt=0;mt<2;++mt)
#pragma unroll
      for (int reg=0;reg<4;++reg){
        int row = mt*16 + q*4 + reg;
        lnS[w][row] = rs[mt][reg];
        lnQ[w][row] = rq[mt][reg];
      }
  }
  __syncthreads();

  const float c0 = 3.0f + alpha[0];
  float mu_[2][4], rstd_[2][4];
#pragma unroll
  for (int mt=0;mt<2;++mt)
#pragma unroll
    for (int reg=0;reg<4;++reg){
      int row = mt*16 + q*4 + reg;
      float S = lnS[0][row]+lnS[1][row]+lnS[2][row]+lnS[3][row];
      float Q = lnQ[0][row]+lnQ[1][row]+lnQ[2][row]+lnQ[3][row];
      float mu = S * (1.f/256.f);
      float var = fmaxf(Q*(1.f/256.f) - mu*mu, 0.f);
      mu_[mt][reg] = mu;
      rstd_[mt][reg] = rsqrtf(var + 1e-5f);
    }

  int e0 = (bx % 48) * 32;
#pragma unroll
  for (int mt=0;mt<2;++mt){
#pragma unroll
    for (int nt=0;nt<4;++nt){
      int gn = w*64 + nt*16 + r;
      float gv = g[gn], bv = bb[gn];
      union{uint16_t u[4]; uint64_t q64;} pk;
#pragma unroll
      for (int reg=0;reg<4;++reg){
        int row = mt*16 + q*4 + reg;
        size_t gm = (size_t)bx*32 + row;
        float o = ((acc[mt][nt][reg]-mu_[mt][reg])*rstd_[mt][reg]*gv + bv) * c0;
        pk.u[reg] = f2bf(o);
        out[gm*256 + gn] = o;
      }
      int ee = e0 + mt*16 + q*4;
      *(uint64_t*)(baset + ((size_t)batch*256 + gn)*1536 + ee) = pk.q64;
    }
  }
}

// ---------------------------------------------------------------------------
// Fused node path (R10):
//   phase 1: W0^T[d,m] = BASET[d,:] . INCB[m,:]  (K=1536, full d=256
//            in-block, m-tile 32, INCB read exactly once) -> As2 bf16 swz
//   phase 2: C2^T[d',m] = WPEB[d',:] . As2[m,:]  (K=256)
//   epilogue: per-m LN over d' + blend with features.
// Grid 256 = 8 batches * 32 m-tiles, XCD-swizzled. LDS 52KB -> 3 blocks/CU.
// ---------------------------------------------------------------------------
__global__ __launch_bounds__(256, 3)
void gemm_node_fused(const uint16_t* __restrict__ inc,    // INCB [8][1024][1536]
                     const uint16_t* __restrict__ baset,  // [8][256][1536]
                     const uint16_t* __restrict__ wpe,    // [256][256]
                     const float* __restrict__ g, const float* __restrict__ bb,
                     const float* __restrict__ alpha,
                     const float* __restrict__ feats, float* __restrict__ out){
  __shared__ short Ws[256*64];    // 32KB: BASET chunk (phase1) / WPEB chunk (phase2)
  __shared__ short As2[32*256];   // 16KB: W0 bf16, swizzled
  __shared__ short Is[32*64];     // 4KB: inc chunk; aliased as lnS/lnQ after phase 2
  const int tid = threadIdx.x;
  const int lane = tid & 63;
  const int w = tid >> 6;
  const int r = lane & 15, q = lane >> 4;
  const int bx = (blockIdx.x & 7)*32 + (blockIdx.x >> 3);  // bijective, 256=8*32
  const int batch = bx >> 5;
  const int mt0 = (bx & 31) * 32;

  const int srow = tid >> 3;   // 0..31
  const int sblk = tid & 7;

  const uint16_t* Bb = baset + (size_t)batch*256*1536;
  const uint16_t* Ib = inc + ((size_t)batch*1024 + mt0)*1536;

  f32x4 acc1[4][2];
#pragma unroll
  for (int i=0;i<4;++i)
#pragma unroll
    for (int j=0;j<2;++j) acc1[i][j] = (f32x4){0.f,0.f,0.f,0.f};

  // ---- phase 1: K=1536 over e ----
  for (int kb = 0; kb < 1536; kb += 64){
#pragma unroll
    for (int i=0;i<8;++i){
      int row = srow + 32*i;
      int lblk = sblk ^ (row & 7);
      load_lds16(Bb + (size_t)row*1536 + kb + lblk*8, (char*)Ws + i*4096 + tid*16);
    }
    { int lblk = sblk ^ (srow & 7);
      load_lds16(Ib + (size_t)srow*1536 + kb + lblk*8, (char*)Is + tid*16); }
    __syncthreads();
#pragma unroll
    for (int kc=0;kc<2;++kc){
      bf16x8 af[4], bfr[2];
#pragma unroll
      for (int mt=0;mt<4;++mt){
        int d = w*64 + mt*16 + r;
        af[mt] = *(const bf16x8*)&Ws[d*64 + ((kc*4 + q) ^ (d&7))*8];
      }
#pragma unroll
      for (int nt=0;nt<2;++nt){
        int m = nt*16 + r;
        bfr[nt] = *(const bf16x8*)&Is[m*64 + ((kc*4 + q) ^ (m&7))*8];
      }
#pragma unroll
      for (int mt=0;mt<4;++mt)
#pragma unroll
        for (int nt=0;nt<2;++nt)
          acc1[mt][nt] = __builtin_amdgcn_mfma_f32_16x16x32_bf16(af[mt], bfr[nt], acc1[mt][nt], 0,0,0);
    }
    __syncthreads();
  }

  // ---- W0^T -> As2[m][d] bf16, 16B-unit XOR swizzle (j ^ (m&7)) ----
  // acc1[mt][nt][reg] = W0^T[d][m], d = w*64+mt*16+q*4+reg, m = nt*16+r.
#pragma unroll
  for (int mt=0;mt<4;++mt){
    int j = w*8 + mt*2 + (q>>1);
#pragma unroll
    for (int nt=0;nt<2;++nt){
      int m = nt*16 + r;
      union{uint16_t u[4]; uint64_t q64;} pk;
#pragma unroll
      for (int reg=0;reg<4;++reg) pk.u[reg] = f2bf(acc1[mt][nt][reg]);
      *(uint64_t*)((char*)As2 + m*512 + ((j ^ (m&7))<<4) + ((q&1)<<3)) = pk.q64;
    }
  }

  // ---- phase 2: K=256 over d, A = WPEB, B = As2 ----
  f32x4 acc2[4][2];
#pragma unroll
  for (int i=0;i<4;++i)
#pragma unroll
    for (int j=0;j<2;++j) acc2[i][j] = (f32x4){0.f,0.f,0.f,0.f};

  for (int kb = 0; kb < 256; kb += 64){
#pragma unroll
    for (int i=0;i<8;++i){
      int row = srow + 32*i;
      int lblk = sblk ^ (row & 7);
      load_lds16(wpe + (size_t)row*256 + kb + lblk*8, (char*)Ws + i*4096 + tid*16);
    }
    __syncthreads();   // orders As2 writes + Ws restage before reads
#pragma unroll
    for (int kc=0;kc<2;++kc){
      bf16x8 af[4], bfr[2];
#pragma unroll
      for (int mt=0;mt<4;++mt){
        int dp = w*64 + mt*16 + r;
        af[mt] = *(const bf16x8*)&Ws[dp*64 + ((kc*4 + q) ^ (dp&7))*8];
      }
#pragma unroll
      for (int nt=0;nt<2;++nt){
        int m = nt*16 + r;
        int jr = (kb>>3) + kc*4 + q;
        bfr[nt] = *(const bf16x8*)((char*)As2 + m*512 + ((jr ^ (m&7))<<4));
      }
#pragma unroll
      for (int mt=0;mt<4;++mt)
#pragma unroll
        for (int nt=0;nt<2;++nt)
          acc2[mt][nt] = __builtin_amdgcn_mfma_f32_16x16x32_bf16(af[mt], bfr[nt], acc2[mt][nt], 0,0,0);
    }
    __syncthreads();
  }

  // ---- LN over d' (per column m), cross-wave via LDS (alias Is) ----
  float* lnS = (float*)Is;        // [4][32]
  float* lnQ = lnS + 128;         // [4][32]
  float s_[2], q_[2];
#pragma unroll
  for (int nt=0;nt<2;++nt){
    float s=0.f, s2=0.f;
#pragma unroll
    for (int mt=0;mt<4;++mt)
#pragma unroll
      for (int reg=0;reg<4;++reg){
        float v = acc2[mt][nt][reg];
        s += v; s2 += v*v;
      }
    s += __shfl_xor(s,16); s2 += __shfl_xor(s2,16);
    s += __shfl_xor(s,32); s2 += __shfl_xor(s2,32);
    s_[nt]=s; q_[nt]=s2;
  }
  if (q == 0){
#pragma unroll
    for (int nt=0;nt<2;++nt){
      lnS[w*32 + nt*16 + r] = s_[nt];
      lnQ[w*32 + nt*16 + r] = q_[nt];
    }
  }
  __syncthreads();

  const float a = alpha[0];
  const float ap1 = 1.f + a;
  const float cn = (1.f - a)*(ap1*ap1 + ap1 + 1.f);
  const float cf = ap1*ap1*ap1;

  float mu_[2], rstd_[2];
#pragma unroll
  for (int nt=0;nt<2;++nt){
    int col = nt*16 + r;
    float S = lnS[col] + lnS[32+col] + lnS[64+col] + lnS[96+col];
    float Q = lnQ[col] + lnQ[32+col] + lnQ[64+col] + lnQ[96+col];
    float mu = S * (1.f/256.f);
    float var = fmaxf(Q*(1.f/256.f) - mu*mu, 0.f);
    mu_[nt] = mu;
    rstd_[nt] = rsqrtf(var + 1e-5f);
  }

  // ---- epilogue: out[m][d'] = cf*feats + cn*LN ----
#pragma unroll
  for (int mt=0;mt<4;++mt){
    int dp0 = w*64 + mt*16 + q*4;
    float4 gv = *(const float4*)&g[dp0];
    float4 bv = *(const float4*)&bb[dp0];
#pragma unroll
    for (int nt=0;nt<2;++nt){
      int m = nt*16 + r;
      size_t gm = (size_t)batch*1024 + mt0 + m;
      float4 fv = *(const float4*)&feats[gm*256 + dp0];
      float4 ov;
      ov.x = cf*fv.x + cn*((acc2[mt][nt][0]-mu_[nt])*rstd_[nt]*gv.x + bv.x);
      ov.y = cf*fv.y + cn*((acc2[mt][nt][1]-mu_[nt])*rstd_[nt]*gv.y + bv.y);
      ov.z = cf*fv.z + cn*((acc2[mt][nt][2]-mu_[nt])*rstd_[nt]*gv.z + bv.z);
      ov.w = cf*fv.w + cn*((acc2[mt][nt][3]-mu_[nt])*rstd_[nt]*gv.w + bv.w);
      *(float4*)&out[gm*256 + dp0] = ov;
    }
  }
}

// ---------------------------------------------------------------------------
// Attention (R10 + T5 setprio): S^T = K*Q^T, packed b64 P-store, scalar l.
// 512 thr = 8 waves x 16 q-rows. grid 512 (1D, XCD-swizzled). Max-free
// softmax; exp2 direct; cvt_pk P-pack.
// ---------------------------------------------------------------------------
DEV void stage_K(short* Kl, const uint16_t* __restrict__ qkv, size_t rowbase,
                 int c, int h, int kr){
  const uint16_t* kp = qkv + ((rowbase + c*256 + kr)*768 + 256 + h*32);
  int sz = (kr&3) ^ ((kr>>2)&1);
#pragma unroll
  for (int lb=0; lb<4; ++lb){
    bf16x8 v = *(const bf16x8*)(kp + lb*8);
    *(bf16x8*)&Kl[kr*32 + ((lb ^ sz))*8] = v;
  }
}

DEV void stage_V(short* VT, const uint16_t* __restrict__ qkv, size_t rowbase,
                 int c, int h, int t){
  int kvp = (t>>1)*2;
  int dhh = (t&1)*16;
  const uint16_t* v0 = qkv + ((rowbase + c*256 + kvp)*768 + 512 + h*32 + dhh);
  const uint16_t* v1 = v0 + 768;
  bf16x8 a0 = *(const bf16x8*)(v0);
  bf16x8 a1 = *(const bf16x8*)(v0+8);
  bf16x8 b0 = *(const bf16x8*)(v1);
  bf16x8 b1 = *(const bf16x8*)(v1+8);
  int blkbase = kvp>>3, off = kvp&7;
#pragma unroll
  for (int i=0;i<8;++i){
    int dh = dhh + i;
    uint32_t pack = (uint32_t)(uint16_t)a0[i] | ((uint32_t)(uint16_t)b0[i]<<16);
    *(uint32_t*)&VT[dh*256 + ((blkbase ^ (dh&7))*8) + off] = pack;
  }
#pragma unroll
  for (int i=0;i<8;++i){
    int dh = dhh + 8 + i;
    uint32_t pack = (uint32_t)(uint16_t)a1[i] | ((uint32_t)(uint16_t)b1[i]<<16);
    *(uint32_t*)&VT[dh*256 + ((blkbase ^ (dh&7))*8) + off] = pack;
  }
}

__global__ __launch_bounds__(512)
void attn_fwd(const uint16_t* __restrict__ qkv, uint16_t* __restrict__ O){
  __shared__ short Kl[256*32];
  __shared__ short VT[32*256];
  __shared__ short Pl[8][16*36];
  const int tid = threadIdx.x, lane = tid&63, w = tid>>6;
  const int r = lane&15, q = lane>>4;
  const int logical = (blockIdx.x & 7)*64 + (blockIdx.x >> 3); // 512=8*64 bijective
  const int bh = logical >> 3, qc = logical & 7;
  const int b = bh>>3, h = bh&7;
  const int q0 = qc*128 + w*16;
  const size_t rowbase = (size_t)b*1024;

  bf16x8 aq;
  {
    // 1/sqrt(32) * log2(e): S_mfma = log2(e) * qk/sqrt(dh) -> p = exp2(S_mfma)
    const float qscale = 0.25505654380651023f;
    const uint16_t* p = qkv + ((rowbase + q0 + r)*768 + h*32 + q*8);
    bf16x8 t = *(const bf16x8*)p;
#pragma unroll
    for (int j=0;j<8;++j)
      t[j] = (short)f2bf(bf2f((uint16_t)t[j]) * qscale);
    aq = t;
  }

  f32x4 o[2];
  o[0]=(f32x4){0.f,0.f,0.f,0.f}; o[1]=(f32x4){0.f,0.f,0.f,0.f};
  float l = 0.f;

  for (int c=0;c<4;++c){
    __syncthreads();
    if (tid < 256) stage_K(Kl, qkv, rowbase, c, h, tid);
    else           stage_V(VT, qkv, rowbase, c, h, tid-256);
    __syncthreads();
    for (int s32=0; s32<8; ++s32){
#pragma unroll
      for (int t2=0;t2<2;++t2){
        int rn = s32*32 + t2*16 + r;
        int sz = (rn&3) ^ ((rn>>2)&1);
        bf16x8 bk = *(const bf16x8*)&Kl[rn*32 + ((q ^ sz))*8];
        f32x4 z = (f32x4){0.f,0.f,0.f,0.f};
        __builtin_amdgcn_s_setprio(1);
        f32x4 st = __builtin_amdgcn_mfma_f32_16x16x32_bf16(bk, aq, z, 0,0,0);
        __builtin_amdgcn_s_setprio(0);
        float p0 = exp2fast(st[0]);
        float p1 = exp2fast(st[1]);
        float p2 = exp2fast(st[2]);
        float p3 = exp2fast(st[3]);
        l += (p0+p1)+(p2+p3);
        union{uint32_t u[2]; uint64_t q64;} pk;
        pk.u[0] = cvtpk_bf16(p0, p1);
        pk.u[1] = cvtpk_bf16(p2, p3);
        *(uint64_t*)&Pl[w][r*36 + t2*16 + q*4] = pk.q64;
      }
      bf16x8 bv[2];
#pragma unroll
      for (int db=0;db<2;++db){
        int dh = db*16 + r;
        bv[db] = *(const bf16x8*)&VT[dh*256 + (((s32*4 + q) ^ (dh&7)))*8];
      }
      bf16x8 ap = *(const bf16x8*)&Pl[w][r*36 + q*8];
      __builtin_amdgcn_s_setprio(1);
#pragma unroll
      for (int db=0;db<2;++db)
        o[db] = __builtin_amdgcn_mfma_f32_16x16x32_bf16(ap, bv[db], o[db], 0,0,0);
      __builtin_amdgcn_s_setprio(0);
    }
  }

  l += __shfl_xor(l, 16);
  l += __shfl_xor(l, 32);
#pragma unroll
  for (int db=0;db<2;++db)
#pragma unroll
    for (int reg=0;reg<4;++reg){
      float li = __shfl(l, q*4 + reg);
      int qr = q0 + q*4 + reg;
      O[(rowbase + qr)*256 + h*32 + db*16 + r] = f2bf(o[db][reg] / li);
    }
}

// ===========================================================================
extern "C" void kernel_launch(void* const* d_in, const int* in_sizes, int n_in,
                              void* d_out, int out_size, void* d_ws, size_t ws_size,
                              hipStream_t stream){
  const float* features = (const float*)d_in[0];
  const float* inc      = (const float*)d_in[1];
  const float* vc_Win   = (const float*)d_in[2];
  const float* vc_bin   = (const float*)d_in[3];
  const float* vc_Wout  = (const float*)d_in[4];
  const float* vc_bout  = (const float*)d_in[5];
  const float* vc_Wproj = (const float*)d_in[6];
  const float* vc_ln_g  = (const float*)d_in[7];
  const float* vc_ln_b  = (const float*)d_in[8];
  const float* vc_alpha = (const float*)d_in[9];
  const float* ec_Wproj = (const float*)d_in[14];
  const float* ec_ln_g  = (const float*)d_in[15];
  const float* ec_ln_b  = (const float*)d_in[16];
  const float* ec_alpha = (const float*)d_in[17];

  float* out = (float*)d_out;
  float* out_node = out;                 // [8,1024,256]
  float* out_edge = out + 2097152;       // [8,1536,256]
  float* out_inc  = out + 5242880;       // [8,1024,1536]

  char* ws = (char*)d_ws;
  uint16_t* XB     = (uint16_t*)(ws + 0);          // 4,194,304 (dead after qkv)
  float*    PART   = (float*)   (ws + 0);          // alias: 393,216 (384*256*4)
  uint16_t* WINB   = (uint16_t*)(ws + 4194304);    // 393,216
  uint16_t* WOUTB  = (uint16_t*)(ws + 4587520);    // 131,072
  uint16_t* WPVB   = (uint16_t*)(ws + 4718592);    // 131,072
  uint16_t* WPEB   = (uint16_t*)(ws + 4849664);    // 131,072
  uint16_t* INCB   = (uint16_t*)(ws + 4988928);    // 25,165,824
  uint16_t* INCT   = (uint16_t*)(ws + 30154752);   // 25,165,824
  uint16_t* QKVB   = (uint16_t*)(ws + 55320576);   // 12,582,912
  uint16_t* SCORESB= (uint16_t*)(ws + 55320576);   // alias: QKVB dead after attn
  uint16_t* OB     = (uint16_t*)(ws + 67903488);   // 4,194,304
  uint16_t* ATTNT  = (uint16_t*)(ws + 72097792);   // 4,194,304
  uint16_t* BASET  = (uint16_t*)(ws + 82583552);   // 6,291,456 (~89 MB total)

  // casts (XB + weights) — must precede qkv GEMM reads
  prep_cast<<<2432,256,0,stream>>>(features, vc_Win, vc_Wout, vc_Wproj, ec_Wproj,
                                   XB, WINB, WOUTB, WPVB, WPEB);

  // fused: qkv GEMM (384 blocks, first) + inc prep (12288 blocks) overlap
  qkv_incprep<<<12672,256,0,stream>>>(inc, out_inc, INCB, INCT,
                                      XB, WINB, QKVB, vc_bin);

  // attention + out-proj (writes ATTNT transposed)
  attn_fwd<<<512,512,0,stream>>>(QKVB, OB);
  gemm_nt<2,128,1><<<dim3(128,2,1),256,0,stream>>>(OB, WOUTB, ATTNT, vc_bout,
                                                   8192,256,256);

  // scores = inc^T @ attn: 32x256 tile (INCT read once), writes VE=v*exp(v)
  // bf16 + 48 exp-sum partials/batch
  gemm_score<<<384,256,0,stream>>>(INCT, ATTNT, PART, SCORESB);

  // edge path: PART->1/L, p=VE/L staging, GEMM, LN, out_edge f32 + BASET bf16
  gemm_ln_edge<<<384,256,0,stream>>>(SCORESB, WPVB, PART, vc_ln_g, vc_ln_b,
                                     vc_alpha, out_edge, BASET);

  // node path: ONE kernel — W0 = inc@base (K=1536, full d in-block) kept in
  // LDS, then @Wpe^T (K=256) + fused LN/blend. 256 blocks.
  gemm_node_fused<<<256,256,0,stream>>>(INCB, BASET, WPEB, ec_ln_g, ec_ln_b,
                                        ec_alpha, features, out_node);
}

// Round 4
// 249.533 us; speedup vs baseline: 1.3154x; 1.0256x over previous
//
#include <hip/hip_runtime.h>
#include <stdint.h>

// ============================================================================
// MessagePassing collapse:
//   e2 = (3+a_vc)*base,  base = LN((scores*softmax_e(scores)) @ Wp_vc^T)
//   n2 = (1+a)^3 * features + (1-a)((1+a)^2+(1+a)+1) * nb,  a = ec_alpha
//   nb = LN((inc @ base) @ Wp_ec^T)  (LN positive-scale-invariant)
//   EC's MHA is dead code.
// R13: (1) ONE front launch: qkv (BK=32, f32->bf16 reg-staging, 16KB LDS)
//      + 4x-fat inc-prep blocks (3072, 4 subtiles/block, T[4] in LDS) +
//      weight-cast blocks (192) — prep_cast launch deleted, LDS union 17KB
//      -> 8 blocks/CU for the write-bound prep (R12: 5, 24% occ, 3.2TB/s).
// (2) Mid-chain grids doubled for latency hiding (1.5 -> 3 blocks/CU):
//      score 32ex128d -> 768 blocks; edge 16mx256d -> 768; node 16m -> 512.
//      Partial-L fold layout unchanged (48 partials/column).
// (3) attn/outproj = R12.
// ============================================================================

#define DEV static __device__ __forceinline__

typedef __attribute__((ext_vector_type(8))) short bf16x8;
typedef __attribute__((ext_vector_type(4))) float f32x4;

DEV uint16_t f2bf(float x){
  union{float f; uint32_t u;} v; v.f=x;
  uint32_t r = v.u + 0x7fffu + ((v.u>>16)&1u);
  return (uint16_t)(r>>16);
}
DEV float bf2f(uint16_t b){
  union{uint32_t u; float f;} v; v.u=((uint32_t)b)<<16; return v.f;
}

DEV uint32_t cvtpk_bf16(float lo, float hi){
  uint32_t d;
  asm("v_cvt_pk_bf16_f32 %0, %1, %2" : "=v"(d) : "v"(lo), "v"(hi));
  return d;
}

#if __has_builtin(__builtin_amdgcn_exp2f)
DEV float exp2fast(float x){ return __builtin_amdgcn_exp2f(x); }
#else
DEV float exp2fast(float x){ return __expf(x * 0.6931471805599453f); }
#endif

#if __has_builtin(__builtin_amdgcn_global_load_lds)
#define HAVE_GLL 1
#else
#define HAVE_GLL 0
#endif

DEV void load_lds16(const uint16_t* g, void* l){
#if HAVE_GLL
  __builtin_amdgcn_global_load_lds((const __attribute__((address_space(1))) uint32_t*)g,
                                   (__attribute__((address_space(3))) uint32_t*)l, 16, 0, 0);
#else
  *(bf16x8*)l = *(const bf16x8*)g;
#endif
}

// ---------------------------------------------------------------------------
// Front launch, 3 block ranges:
//  [0,384):      qkv GEMM C[8192,768] = feats(f32)@Win(f32)^T + bin, bf16
//                accumulate path; tile 128x128, BK=32, reg-staged f32->bf16.
//  [384,3456):   inc prep, 4x fat: each block does 32rows x 128cols
//                (copy f32 out + bf16 + bf16^T), T[4][32][33] in LDS.
//  [3456,3648):  Wout/Wpv/Wpe f32->bf16 casts (49152 f4 units).
// ---------------------------------------------------------------------------
__global__ __launch_bounds__(256, 3)
void qkv_prep(const float* __restrict__ inc, float* __restrict__ out_inc,
              uint16_t* __restrict__ incb, uint16_t* __restrict__ incT,
              const float* __restrict__ feats, const float* __restrict__ win,
              const float* __restrict__ bias, uint16_t* __restrict__ qkvb,
              const float* __restrict__ wout, const float* __restrict__ wpv,
              const float* __restrict__ wpe,
              uint16_t* __restrict__ ob_w, uint16_t* __restrict__ ov_w,
              uint16_t* __restrict__ oe_w){
  __shared__ union {
    struct { short As[128*32]; short Bs[128*32]; } g;   // 16 KB
    float T[4][32][33];                                 // 16.9 KB
  } sm;
  const int tid = threadIdx.x;
  const int bx = blockIdx.x;

  if (bx < 384){
    // ---- qkv GEMM, BK=32 ----
    const int lane = tid & 63;
    const int w = tid >> 6;
    const int wm = w & 1, wn = w >> 1;
    const int r = lane & 15, q = lane >> 4;
    const int mtile = bx & 63, ntile = bx >> 6;   // 64 x 6
    const float* Fb = feats + (size_t)(mtile*128)*256;
    const float* Wb = win + (size_t)(ntile*128)*256;
    f32x4 acc[4][4];
#pragma unroll
    for (int i=0;i<4;++i)
#pragma unroll
      for (int j=0;j<4;++j) acc[i][j] = (f32x4){0.f,0.f,0.f,0.f};

    const int srow = tid >> 2;   // 0..63
    const int sblk = tid & 3;    // 0..3 (units of 8 bf16 within BK=32)

    for (int kb = 0; kb < 256; kb += 32){
#pragma unroll
      for (int i=0;i<2;++i){
        int row = srow + 64*i;
        const float* src = Fb + (size_t)row*256 + kb + sblk*8;
        float4 a0 = *(const float4*)src;
        float4 a1 = *(const float4*)(src+4);
        union{uint32_t u[4]; bf16x8 v8;} pk;
        pk.u[0]=cvtpk_bf16(a0.x,a0.y); pk.u[1]=cvtpk_bf16(a0.z,a0.w);
        pk.u[2]=cvtpk_bf16(a1.x,a1.y); pk.u[3]=cvtpk_bf16(a1.z,a1.w);
        *(bf16x8*)&sm.g.As[row*32 + (sblk ^ (row&3))*8] = pk.v8;
      }
#pragma unroll
      for (int i=0;i<2;++i){
        int row = srow + 64*i;
        const float* src = Wb + (size_t)row*256 + kb + sblk*8;
        float4 a0 = *(const float4*)src;
        float4 a1 = *(const float4*)(src+4);
        union{uint32_t u[4]; bf16x8 v8;} pk;
        pk.u[0]=cvtpk_bf16(a0.x,a0.y); pk.u[1]=cvtpk_bf16(a0.z,a0.w);
        pk.u[2]=cvtpk_bf16(a1.x,a1.y); pk.u[3]=cvtpk_bf16(a1.z,a1.w);
        *(bf16x8*)&sm.g.Bs[row*32 + (sblk ^ (row&3))*8] = pk.v8;
      }
      __syncthreads();
      bf16x8 af[4], bfr[4];
#pragma unroll
      for (int mt=0;mt<4;++mt){
        int m = wm*64 + mt*16 + r;
        af[mt] = *(const bf16x8*)&sm.g.As[m*32 + (q ^ (m&3))*8];
      }
#pragma unroll
      for (int nt=0;nt<4;++nt){
        int n = wn*64 + nt*16 + r;
        bfr[nt] = *(const bf16x8*)&sm.g.Bs[n*32 + (q ^ (n&3))*8];
      }
#pragma unroll
      for (int mt=0;mt<4;++mt)
#pragma unroll
        for (int nt=0;nt<4;++nt)
          acc[mt][nt] = __builtin_amdgcn_mfma_f32_16x16x32_bf16(af[mt], bfr[nt], acc[mt][nt], 0,0,0);
      __syncthreads();
    }

    const int gm0 = mtile*128 + wm*64;
    const int gn0 = ntile*128 + wn*64;
#pragma unroll
    for (int mt=0;mt<4;++mt){
#pragma unroll
      for (int nt=0;nt<4;++nt){
        int gn = gn0 + nt*16 + r;
        float bv = bias[gn];
#pragma unroll
        for (int reg=0;reg<4;++reg){
          int gm = gm0 + mt*16 + q*4 + reg;   // C/D: col=lane&15, row=quad*4+reg
          qkvb[(size_t)gm*768 + gn] = f2bf(acc[mt][nt][reg] + bv);
        }
      }
    }
  } else if (bx < 3456){
    // ---- inc prep, 4 subtiles per block ----
    int p = bx - 384;
    int x = p % 12;             // 128-col group
    int t = p / 12;
    int y = t % 32;             // 32-row tile
    int b = t / 32;             // batch
    int r0 = y*32;
    int tx = tid & 31, ty = tid >> 5;
    size_t base = (size_t)b*1024*1536;
    size_t baseT = (size_t)b*1536*1024;
#pragma unroll
    for (int s=0;s<4;++s){
      int c0 = x*128 + s*32;
#pragma unroll
      for (int j=0;j<4;++j){
        int rr = r0 + ty + j*8;
        size_t idx = base + (size_t)rr*1536 + c0 + tx;
        float v = inc[idx];
        sm.T[s][ty+j*8][tx] = v;
        out_inc[idx] = v;
        incb[idx] = f2bf(v);
      }
    }
    __syncthreads();
#pragma unroll
    for (int s=0;s<4;++s){
      int c0 = x*128 + s*32;
#pragma unroll
      for (int j=0;j<4;++j){
        int c = c0 + ty + j*8;
        incT[baseT + (size_t)c*1024 + r0 + tx] = f2bf(sm.T[s][tx][ty+j*8]);
      }
    }
  } else {
    // ---- weight casts: Wout/Wpv/Wpe, 16384 f4-units each ----
    int i = (bx - 3456)*256 + tid;
    const float* src; uint16_t* dst; int j;
    if (i < 16384){ src=wout; dst=ob_w; j=i; }
    else if (i < 32768){ src=wpv; dst=ov_w; j=i-16384; }
    else { src=wpe; dst=oe_w; j=i-32768; }
    float4 v = ((const float4*)src)[j];
    union { uint16_t u[4]; uint64_t q; } p;
    p.u[0]=f2bf(v.x); p.u[1]=f2bf(v.y); p.u[2]=f2bf(v.z); p.u[3]=f2bf(v.w);
    ((uint64_t*)dst)[j] = p.q;
  }
}

// ---------------------------------------------------------------------------
// NT bf16 GEMM (LDS-staged): C[M,N] = A[M,K]*B[N,K]^T (+bias).
// EPI 1 = transposed bf16 store (per-batch [N][1024]). Used for outproj.
// ---------------------------------------------------------------------------
template<int WM, int BK, int EPI>
__global__ __launch_bounds__(256, 3)
void gemm_nt(const uint16_t* __restrict__ A, const uint16_t* __restrict__ B,
             uint16_t* __restrict__ Cb, const float* __restrict__ bias,
             int M, int N, int K){
  constexpr int AROWS = WM*32;
  constexpr int UPR = BK/8;
  constexpr int RPP = 256/UPR;
  __shared__ short As[AROWS*BK];
  __shared__ short Bs[128*BK];
  const int tid = threadIdx.x;
  const int lane = tid & 63;
  const int w = tid >> 6;
  const int wm = w & 1, wn = w >> 1;
  const int r = lane & 15, q = lane >> 4;
  const uint16_t* Ab = A + (size_t)(blockIdx.x*AROWS)*K;
  const uint16_t* Bb = B + (size_t)(blockIdx.y*128)*K;
  f32x4 acc[WM][4];
#pragma unroll
  for (int i=0;i<WM;++i)
#pragma unroll
    for (int j=0;j<4;++j) acc[i][j] = (f32x4){0.f,0.f,0.f,0.f};

  const int srow = tid / UPR;
  const int sblk = tid % UPR;

  for (int kb = 0; kb < K; kb += BK){
#pragma unroll
    for (int i=0;i<AROWS/RPP;++i){
      int row = srow + RPP*i;
      int lblk = sblk ^ (row & (UPR-1));
      load_lds16(Ab + (size_t)row*K + kb + lblk*8, (char*)As + i*4096 + tid*16);
    }
#pragma unroll
    for (int i=0;i<128/RPP;++i){
      int row = srow + RPP*i;
      int lblk = sblk ^ (row & (UPR-1));
      load_lds16(Bb + (size_t)row*K + kb + lblk*8, (char*)Bs + i*4096 + tid*16);
    }
    __syncthreads();
#pragma unroll
    for (int kc=0;kc<BK/32;++kc){
      bf16x8 af[WM], bfr[4];
#pragma unroll
      for (int mt=0;mt<WM;++mt){
        int m = wm*(WM*16) + mt*16 + r;
        af[mt] = *(const bf16x8*)&As[m*BK + ((kc*4 + q) ^ (m&(UPR-1)))*8];
      }
#pragma unroll
      for (int nt=0;nt<4;++nt){
        int n = wn*64 + nt*16 + r;
        bfr[nt] = *(const bf16x8*)&Bs[n*BK + ((kc*4 + q) ^ (n&(UPR-1)))*8];
      }
#pragma unroll
      for (int mt=0;mt<WM;++mt)
#pragma unroll
        for (int nt=0;nt<4;++nt)
          acc[mt][nt] = __builtin_amdgcn_mfma_f32_16x16x32_bf16(af[mt], bfr[nt], acc[mt][nt], 0,0,0);
    }
    __syncthreads();
  }

  const int gm0 = blockIdx.x*AROWS + wm*(WM*16);
  const int gn0 = blockIdx.y*128 + wn*64;

  if constexpr (EPI == 1){
#pragma unroll
    for (int mt=0;mt<WM;++mt){
      int gmb = gm0 + mt*16 + q*4;
      size_t bb_ = (size_t)(gmb>>10)*(256*1024);
      int mm = gmb & 1023;
#pragma unroll
      for (int nt=0;nt<4;++nt){
        int gn = gn0 + nt*16 + r;
        float bv = bias ? bias[gn] : 0.f;
        union{uint16_t u[4]; uint64_t q64;} pk;
#pragma unroll
        for (int reg=0;reg<4;++reg) pk.u[reg] = f2bf(acc[mt][nt][reg] + bv);
        *(uint64_t*)(Cb + bb_ + (size_t)gn*1024 + mm) = pk.q64;
      }
    }
  } else {
#pragma unroll
    for (int mt=0;mt<WM;++mt){
#pragma unroll
      for (int nt=0;nt<4;++nt){
        int gn = gn0 + nt*16 + r;
        float bv = bias ? bias[gn] : 0.f;
#pragma unroll
        for (int reg=0;reg<4;++reg){
          int gm = gm0 + mt*16 + q*4 + reg;
          Cb[(size_t)gm*N + gn] = f2bf(acc[mt][nt][reg] + bv);
        }
      }
    }
  }
}

// ---------------------------------------------------------------------------
// scores GEMM: C[e,d] = incT[e,:].attnT[d,:] (K=1024). Tile 32e x 128d,
// 4 waves x 32 cols. Grid 768 = 8 batches * 48 etiles * 2 dhalves,
// XCD-swizzled. Writes VE=v*exp(v) bf16 + column exp-sum partials
// (48 partials per column, layout part[batch][48][256] — dh blocks write
// disjoint 128-col halves).
// ---------------------------------------------------------------------------
__global__ __launch_bounds__(256, 4)
void gemm_score(const uint16_t* __restrict__ A,   // INCT flat [8*1536][1024]
                const uint16_t* __restrict__ B,   // ATTNT [8][256][1024]
                float* __restrict__ part,         // [8][48][256]
                uint16_t* __restrict__ VE){       // [8*1536][256]
  __shared__ short As[32*64];     // 4 KB
  __shared__ short Bs[128*64];    // 16 KB
  const int tid = threadIdx.x;
  const int lane = tid & 63;
  const int w = tid >> 6;
  const int r = lane & 15, q = lane >> 4;
  const int bx = (blockIdx.x & 7)*96 + (blockIdx.x >> 3);   // bijective, 768=8*96
  const int batch = bx / 96;
  const int t = bx % 96;
  const int etile = t >> 1, dh = t & 1;
  const uint16_t* Ab = A + (size_t)(batch*1536 + etile*32)*1024;
  const uint16_t* Bb = B + (size_t)(batch*256 + dh*128)*1024;

  f32x4 acc[2][2];
#pragma unroll
  for (int i=0;i<2;++i)
#pragma unroll
    for (int j=0;j<2;++j) acc[i][j] = (f32x4){0.f,0.f,0.f,0.f};

  const int srow = tid >> 3;   // 0..31
  const int sblk = tid & 7;

  for (int kb = 0; kb < 1024; kb += 64){
    { int lblk = sblk ^ (srow & 7);
      load_lds16(Ab + (size_t)srow*1024 + kb + lblk*8, (char*)As + tid*16); }
#pragma unroll
    for (int i=0;i<4;++i){
      int row = srow + 32*i;
      int lblk = sblk ^ (row & 7);
      load_lds16(Bb + (size_t)row*1024 + kb + lblk*8, (char*)Bs + i*4096 + tid*16);
    }
    __syncthreads();
#pragma unroll
    for (int kc=0;kc<2;++kc){
      bf16x8 af[2], bfr[2];
#pragma unroll
      for (int mt=0;mt<2;++mt){
        int m = mt*16 + r;
        af[mt] = *(const bf16x8*)&As[m*64 + ((kc*4 + q) ^ (m&7))*8];
      }
#pragma unroll
      for (int nt=0;nt<2;++nt){
        int n = w*32 + nt*16 + r;
        bfr[nt] = *(const bf16x8*)&Bs[n*64 + ((kc*4 + q) ^ (n&7))*8];
      }
#pragma unroll
      for (int mt=0;mt<2;++mt)
#pragma unroll
        for (int nt=0;nt<2;++nt)
          acc[mt][nt] = __builtin_amdgcn_mfma_f32_16x16x32_bf16(af[mt], bfr[nt], acc[mt][nt], 0,0,0);
    }
    __syncthreads();
  }

  const size_t er0 = (size_t)batch*1536 + etile*32;
#pragma unroll
  for (int nt=0;nt<2;++nt){
    int gn = dh*128 + w*32 + nt*16 + r;
    float s = 0.f;
#pragma unroll
    for (int mt=0;mt<2;++mt){
#pragma unroll
      for (int reg=0;reg<4;++reg){
        float v = acc[mt][nt][reg];
        float ev = __expf(v);
        s += ev;
        int row = mt*16 + q*4 + reg;
        VE[(er0 + row)*256 + gn] = f2bf(v*ev);
      }
    }
    s += __shfl_xor(s, 16);
    s += __shfl_xor(s, 32);
    if (q == 0) part[(size_t)(batch*48 + etile)*256 + gn] = s;
  }
}

// ---------------------------------------------------------------------------
// Edge path: A = VE * (1/L) staged (cvt_pk), L folded from 48 partials.
// Tile 16m x 256n (LN over full 256 in-block), grid 768 = 8*96, XCD-swizzled.
// Writes out_edge f32 + BASET bf16 [b][d][e].
// ---------------------------------------------------------------------------
__global__ __launch_bounds__(256, 4)
void gemm_ln_edge(const uint16_t* __restrict__ SB, const uint16_t* __restrict__ B,
                  const float* __restrict__ part, const float* __restrict__ g,
                  const float* __restrict__ bb, const float* __restrict__ alpha,
                  float* __restrict__ out, uint16_t* __restrict__ baset){
  __shared__ short As[16*64];     // 2 KB
  __shared__ short Bs[256*64];    // 32 KB
  __shared__ float lnS[4][16], lnQ[4][16];
  __shared__ float PLinv[256];
  const int tid = threadIdx.x;
  const int lane = tid & 63;
  const int w = tid >> 6;          // wave = d-strip 0..3
  const int r = lane & 15, q = lane >> 4;
  const int bx = (blockIdx.x & 7)*96 + (blockIdx.x >> 3);   // 768=8*96
  const int batch = bx / 96;

  {
    float s = 0.f;
#pragma unroll
    for (int i=0;i<48;++i) s += part[((size_t)batch*48 + i)*256 + tid];
    PLinv[tid] = 1.0f / s;
  }
  __syncthreads();

  f32x4 acc[4];
#pragma unroll
  for (int j=0;j<4;++j) acc[j] = (f32x4){0.f,0.f,0.f,0.f};

  const int srow = tid >> 3;   // 0..31 (A uses 0..15 via tid<128)
  const int sblk = tid & 7;

  for (int kb = 0; kb < 256; kb += 64){
    if (tid < 128){
      bf16x8 v = *(const bf16x8*)(SB + (size_t)(bx*16 + srow)*256 + kb + sblk*8);
      const float* Lp = &PLinv[kb + sblk*8];
      float xv[8];
#pragma unroll
      for (int j=0;j<8;++j) xv[j] = bf2f((uint16_t)v[j]) * Lp[j];
      union{uint32_t u[4]; bf16x8 v8;} pk;
      pk.u[0] = cvtpk_bf16(xv[0], xv[1]);
      pk.u[1] = cvtpk_bf16(xv[2], xv[3]);
      pk.u[2] = cvtpk_bf16(xv[4], xv[5]);
      pk.u[3] = cvtpk_bf16(xv[6], xv[7]);
      *(bf16x8*)&As[srow*64 + (sblk ^ (srow&7))*8] = pk.v8;
    }
#pragma unroll
    for (int i=0;i<8;++i){
      int row = srow + 32*i;
      int lblk = sblk ^ (row & 7);
      load_lds16(B + (size_t)row*256 + kb + lblk*8, (char*)Bs + i*4096 + tid*16);
    }
    __syncthreads();
#pragma unroll
    for (int kc=0;kc<2;++kc){
      bf16x8 af, bfr[4];
      { int m = r;
        af = *(const bf16x8*)&As[m*64 + ((kc*4 + q) ^ (m&7))*8]; }
#pragma unroll
      for (int nt=0;nt<4;++nt){
        int n = w*64 + nt*16 + r;
        bfr[nt] = *(const bf16x8*)&Bs[n*64 + ((kc*4 + q) ^ (n&7))*8];
      }
#pragma unroll
      for (int nt=0;nt<4;++nt)
        acc[nt] = __builtin_amdgcn_mfma_f32_16x16x32_bf16(af, bfr[nt], acc[nt], 0,0,0);
    }
    __syncthreads();
  }

  // cross-wave LN reduction (rows = q*4+reg, 16 rows)
  float rs[4], rq[4];
#pragma unroll
  for (int reg=0;reg<4;++reg){
    float s=0.f, s2=0.f;
#pragma unroll
    for (int nt=0;nt<4;++nt){
      float v = acc[nt][reg];
      s += v; s2 += v*v;
    }
#pragma unroll
    for (int off=1; off<16; off<<=1){ s += __shfl_xor(s,off); s2 += __shfl_xor(s2,off); }
    rs[reg]=s; rq[reg]=s2;
  }
  if (r == 0){
#pragma unroll
    for (int reg=0;reg<4;++reg){
      int row = q*4 + reg;
      lnS[w][row] = rs[reg];
      lnQ[w][row] = rq[reg];
    }
  }
  __syncthreads();

  const float c0 = 3.0f + alpha[0];
  float mu_[4], rstd_[4];
#pragma unroll
  for (int reg=0;reg<4;++reg){
    int row = q*4 + reg;
    float S = lnS[0][row]+lnS[1][row]+lnS[2][row]+lnS[3][row];
    float Q = lnQ[0][row]+lnQ[1][row]+lnQ[2][row]+lnQ[3][row];
    float mu = S * (1.f/256.f);
    float var = fmaxf(Q*(1.f/256.f) - mu*mu, 0.f);
    mu_[reg] = mu;
    rstd_[reg] = rsqrtf(var + 1e-5f);
  }

  int e0 = (bx % 96) * 16;
#pragma unroll
  for (int nt=0;nt<4;++nt){
    int gn = w*64 + nt*16 + r;
    float gv = g[gn], bv = bb[gn];
    union{uint16_t u[4]; uint64_t q64;} pk;
#pragma unroll
    for (int reg=0;reg<4;++reg){
      int row = q*4 + reg;
      size_t gm = (size_t)bx*16 + row;
      float o = ((acc[nt][reg]-mu_[reg])*rstd_[reg]*gv + bv) * c0;
      pk.u[reg] = f2bf(o);
      out[gm*256 + gn] = o;
    }
    int ee = e0 + q*4;
    *(uint64_t*)(baset + ((size_t)batch*256 + gn)*1536 + ee) = pk.q64;
  }
}

// ---------------------------------------------------------------------------
// Fused node path: 16m x 256d tiles, grid 512 = 8 batches * 64 m-tiles,
// XCD-swizzled.
//   phase 1: W0^T[d,m] = BASET[d,:].INCB[m,:] (K=1536) -> As2 bf16 swz
//   phase 2: C2^T[d',m] = WPEB[d',:].As2[m,:] (K=256)
//   epilogue: per-m LN over d' + blend with features.
// ---------------------------------------------------------------------------
__global__ __launch_bounds__(256, 3)
void gemm_node_fused(const uint16_t* __restrict__ inc,    // INCB [8][1024][1536]
                     const uint16_t* __restrict__ baset,  // [8][256][1536]
                     const uint16_t* __restrict__ wpe,    // [256][256]
                     const float* __restrict__ g, const float* __restrict__ bb,
                     const float* __restrict__ alpha,
                     const float* __restrict__ feats, float* __restrict__ out){
  __shared__ short Ws[256*64];    // 32KB
  __shared__ short As2[16*256];   // 8KB: W0 bf16, swizzled
  __shared__ short Is[16*64];     // 2KB: inc chunk; aliased lnS/lnQ later
  const int tid = threadIdx.x;
  const int lane = tid & 63;
  const int w = tid >> 6;
  const int r = lane & 15, q = lane >> 4;
  const int bx = (blockIdx.x & 7)*64 + (blockIdx.x >> 3);  // bijective, 512=8*64
  const int batch = bx >> 6;
  const int mt0 = (bx & 63) * 16;

  const int srow = tid >> 3;   // 0..31
  const int sblk = tid & 7;

  const uint16_t* Bb = baset + (size_t)batch*256*1536;
  const uint16_t* Ib = inc + ((size_t)batch*1024 + mt0)*1536;

  f32x4 acc1[4];
#pragma unroll
  for (int i=0;i<4;++i) acc1[i] = (f32x4){0.f,0.f,0.f,0.f};

  // ---- phase 1: K=1536 ----
  for (int kb = 0; kb < 1536; kb += 64){
#pragma unroll
    for (int i=0;i<8;++i){
      int row = srow + 32*i;
      int lblk = sblk ^ (row & 7);
      load_lds16(Bb + (size_t)row*1536 + kb + lblk*8, (char*)Ws + i*4096 + tid*16);
    }
    if (tid < 128){
      int lblk = sblk ^ (srow & 7);
      load_lds16(Ib + (size_t)srow*1536 + kb + lblk*8, (char*)Is + tid*16);
    }
    __syncthreads();
#pragma unroll
    for (int kc=0;kc<2;++kc){
      bf16x8 af[4], bfr;
#pragma unroll
      for (int mt=0;mt<4;++mt){
        int d = w*64 + mt*16 + r;
        af[mt] = *(const bf16x8*)&Ws[d*64 + ((kc*4 + q) ^ (d&7))*8];
      }
      { int m = r;
        bfr = *(const bf16x8*)&Is[m*64 + ((kc*4 + q) ^ (m&7))*8]; }
#pragma unroll
      for (int mt=0;mt<4;++mt)
        acc1[mt] = __builtin_amdgcn_mfma_f32_16x16x32_bf16(af[mt], bfr, acc1[mt], 0,0,0);
    }
    __syncthreads();
  }

  // ---- W0^T -> As2[m][d] bf16, 16B-unit XOR swizzle (j ^ (m&7)) ----
  // acc1[mt][reg] = W0^T[d][m], d = w*64+mt*16+q*4+reg, m = r.
#pragma unroll
  for (int mt=0;mt<4;++mt){
    int j = w*8 + mt*2 + (q>>1);
    int m = r;
    union{uint16_t u[4]; uint64_t q64;} pk;
#pragma unroll
    for (int reg=0;reg<4;++reg) pk.u[reg] = f2bf(acc1[mt][reg]);
    *(uint64_t*)((char*)As2 + m*512 + ((j ^ (m&7))<<4) + ((q&1)<<3)) = pk.q64;
  }

  // ---- phase 2: K=256, A = WPEB, B = As2 ----
  f32x4 acc2[4];
#pragma unroll
  for (int i=0;i<4;++i) acc2[i] = (f32x4){0.f,0.f,0.f,0.f};

  for (int kb = 0; kb < 256; kb += 64){
#pragma unroll
    for (int i=0;i<8;++i){
      int row = srow + 32*i;
      int lblk = sblk ^ (row & 7);
      load_lds16(wpe + (size_t)row*256 + kb + lblk*8, (char*)Ws + i*4096 + tid*16);
    }
    __syncthreads();   // orders As2 writes + Ws restage before reads
#pragma unroll
    for (int kc=0;kc<2;++kc){
      bf16x8 af[4], bfr;
#pragma unroll
      for (int mt=0;mt<4;++mt){
        int dp = w*64 + mt*16 + r;
        af[mt] = *(const bf16x8*)&Ws[dp*64 + ((kc*4 + q) ^ (dp&7))*8];
      }
      { int m = r;
        int jr = (kb>>3) + kc*4 + q;
        bfr = *(const bf16x8*)((char*)As2 + m*512 + ((jr ^ (m&7))<<4)); }
#pragma unroll
      for (int mt=0;mt<4;++mt)
        acc2[mt] = __builtin_amdgcn_mfma_f32_16x16x32_bf16(af[mt], bfr, acc2[mt], 0,0,0);
    }
    __syncthreads();
  }

  // ---- LN over d' (per column m = r), cross-wave via LDS (alias Is) ----
  float* lnS = (float*)Is;        // [4][16]
  float* lnQ = lnS + 64;          // [4][16]
  float s_, q_;
  {
    float s=0.f, s2=0.f;
#pragma unroll
    for (int mt=0;mt<4;++mt)
#pragma unroll
      for (int reg=0;reg<4;++reg){
        float v = acc2[mt][reg];
        s += v; s2 += v*v;
      }
    s += __shfl_xor(s,16); s2 += __shfl_xor(s2,16);
    s += __shfl_xor(s,32); s2 += __shfl_xor(s2,32);
    s_ = s; q_ = s2;
  }
  if (q == 0){
    lnS[w*16 + r] = s_;
    lnQ[w*16 + r] = q_;
  }
  __syncthreads();

  const float a = alpha[0];
  const float ap1 = 1.f + a;
  const float cn = (1.f - a)*(ap1*ap1 + ap1 + 1.f);
  const float cf = ap1*ap1*ap1;

  float mu_, rstd_;
  {
    int col = r;
    float S = lnS[col] + lnS[16+col] + lnS[32+col] + lnS[48+col];
    float Q = lnQ[col] + lnQ[16+col] + lnQ[32+col] + lnQ[48+col];
    float mu = S * (1.f/256.f);
    float var = fmaxf(Q*(1.f/256.f) - mu*mu, 0.f);
    mu_ = mu;
    rstd_ = rsqrtf(var + 1e-5f);
  }

  // ---- epilogue: out[m][d'] = cf*feats + cn*LN ----
#pragma unroll
  for (int mt=0;mt<4;++mt){
    int dp0 = w*64 + mt*16 + q*4;
    float4 gv = *(const float4*)&g[dp0];
    float4 bv = *(const float4*)&bb[dp0];
    int m = r;
    size_t gm = (size_t)batch*1024 + mt0 + m;
    float4 fv = *(const float4*)&feats[gm*256 + dp0];
    float4 ov;
    ov.x = cf*fv.x + cn*((acc2[mt][0]-mu_)*rstd_*gv.x + bv.x);
    ov.y = cf*fv.y + cn*((acc2[mt][1]-mu_)*rstd_*gv.y + bv.y);
    ov.z = cf*fv.z + cn*((acc2[mt][2]-mu_)*rstd_*gv.z + bv.z);
    ov.w = cf*fv.w + cn*((acc2[mt][3]-mu_)*rstd_*gv.w + bv.w);
    *(float4*)&out[gm*256 + dp0] = ov;
  }
}

// ---------------------------------------------------------------------------
// Attention (unchanged from R12): S^T = K*Q^T, packed b64 P-store, scalar l.
// 512 thr = 8 waves x 16 q-rows. grid 512 (1D, XCD-swizzled). Max-free
// softmax; exp2 direct; cvt_pk P-pack; setprio around MFMA (T5).
// ---------------------------------------------------------------------------
DEV void stage_K(short* Kl, const uint16_t* __restrict__ qkv, size_t rowbase,
                 int c, int h, int kr){
  const uint16_t* kp = qkv + ((rowbase + c*256 + kr)*768 + 256 + h*32);
  int sz = (kr&3) ^ ((kr>>2)&1);
#pragma unroll
  for (int lb=0; lb<4; ++lb){
    bf16x8 v = *(const bf16x8*)(kp + lb*8);
    *(bf16x8*)&Kl[kr*32 + ((lb ^ sz))*8] = v;
  }
}

DEV void stage_V(short* VT, const uint16_t* __restrict__ qkv, size_t rowbase,
                 int c, int h, int t){
  int kvp = (t>>1)*2;
  int dhh = (t&1)*16;
  const uint16_t* v0 = qkv + ((rowbase + c*256 + kvp)*768 + 512 + h*32 + dhh);
  const uint16_t* v1 = v0 + 768;
  bf16x8 a0 = *(const bf16x8*)(v0);
  bf16x8 a1 = *(const bf16x8*)(v0+8);
  bf16x8 b0 = *(const bf16x8*)(v1);
  bf16x8 b1 = *(const bf16x8*)(v1+8);
  int blkbase = kvp>>3, off = kvp&7;
#pragma unroll
  for (int i=0;i<8;++i){
    int dh = dhh + i;
    uint32_t pack = (uint32_t)(uint16_t)a0[i] | ((uint32_t)(uint16_t)b0[i]<<16);
    *(uint32_t*)&VT[dh*256 + ((blkbase ^ (dh&7))*8) + off] = pack;
  }
#pragma unroll
  for (int i=0;i<8;++i){
    int dh = dhh + 8 + i;
    uint32_t pack = (uint32_t)(uint16_t)a1[i] | ((uint32_t)(uint16_t)b1[i]<<16);
    *(uint32_t*)&VT[dh*256 + ((blkbase ^ (dh&7))*8) + off] = pack;
  }
}

__global__ __launch_bounds__(512)
void attn_fwd(const uint16_t* __restrict__ qkv, uint16_t* __restrict__ O){
  __shared__ short Kl[256*32];
  __shared__ short VT[32*256];
  __shared__ short Pl[8][16*36];
  const int tid = threadIdx.x, lane = tid&63, w = tid>>6;
  const int r = lane&15, q = lane>>4;
  const int logical = (blockIdx.x & 7)*64 + (blockIdx.x >> 3); // 512=8*64 bijective
  const int bh = logical >> 3, qc = logical & 7;
  const int b = bh>>3, h = bh&7;
  const int q0 = qc*128 + w*16;
  const size_t rowbase = (size_t)b*1024;

  bf16x8 aq;
  {
    // 1/sqrt(32) * log2(e): p = exp2(S_mfma)
    const float qscale = 0.25505654380651023f;
    const uint16_t* p = qkv + ((rowbase + q0 + r)*768 + h*32 + q*8);
    bf16x8 t = *(const bf16x8*)p;
#pragma unroll
    for (int j=0;j<8;++j)
      t[j] = (short)f2bf(bf2f((uint16_t)t[j]) * qscale);
    aq = t;
  }

  f32x4 o[2];
  o[0]=(f32x4){0.f,0.f,0.f,0.f}; o[1]=(f32x4){0.f,0.f,0.f,0.f};
  float l = 0.f;

  for (int c=0;c<4;++c){
    __syncthreads();
    if (tid < 256) stage_K(Kl, qkv, rowbase, c, h, tid);
    else           stage_V(VT, qkv, rowbase, c, h, tid-256);
    __syncthreads();
    for (int s32=0; s32<8; ++s32){
#pragma unroll
      for (int t2=0;t2<2;++t2){
        int rn = s32*32 + t2*16 + r;
        int sz = (rn&3) ^ ((rn>>2)&1);
        bf16x8 bk = *(const bf16x8*)&Kl[rn*32 + ((q ^ sz))*8];
        f32x4 z = (f32x4){0.f,0.f,0.f,0.f};
        __builtin_amdgcn_s_setprio(1);
        f32x4 st = __builtin_amdgcn_mfma_f32_16x16x32_bf16(bk, aq, z, 0,0,0);
        __builtin_amdgcn_s_setprio(0);
        float p0 = exp2fast(st[0]);
        float p1 = exp2fast(st[1]);
        float p2 = exp2fast(st[2]);
        float p3 = exp2fast(st[3]);
        l += (p0+p1)+(p2+p3);
        union{uint32_t u[2]; uint64_t q64;} pk;
        pk.u[0] = cvtpk_bf16(p0, p1);
        pk.u[1] = cvtpk_bf16(p2, p3);
        *(uint64_t*)&Pl[w][r*36 + t2*16 + q*4] = pk.q64;
      }
      bf16x8 bv[2];
#pragma unroll
      for (int db=0;db<2;++db){
        int dh = db*16 + r;
        bv[db] = *(const bf16x8*)&VT[dh*256 + (((s32*4 + q) ^ (dh&7)))*8];
      }
      bf16x8 ap = *(const bf16x8*)&Pl[w][r*36 + q*8];
      __builtin_amdgcn_s_setprio(1);
#pragma unroll
      for (int db=0;db<2;++db)
        o[db] = __builtin_amdgcn_mfma_f32_16x16x32_bf16(ap, bv[db], o[db], 0,0,0);
      __builtin_amdgcn_s_setprio(0);
    }
  }

  l += __shfl_xor(l, 16);
  l += __shfl_xor(l, 32);
#pragma unroll
  for (int db=0;db<2;++db)
#pragma unroll
    for (int reg=0;reg<4;++reg){
      float li = __shfl(l, q*4 + reg);
      int qr = q0 + q*4 + reg;
      O[(rowbase + qr)*256 + h*32 + db*16 + r] = f2bf(o[db][reg] / li);
    }
}

// ===========================================================================
extern "C" void kernel_launch(void* const* d_in, const int* in_sizes, int n_in,
                              void* d_out, int out_size, void* d_ws, size_t ws_size,
                              hipStream_t stream){
  const float* features = (const float*)d_in[0];
  const float* inc      = (const float*)d_in[1];
  const float* vc_Win   = (const float*)d_in[2];
  const float* vc_bin   = (const float*)d_in[3];
  const float* vc_Wout  = (const float*)d_in[4];
  const float* vc_bout  = (const float*)d_in[5];
  const float* vc_Wproj = (const float*)d_in[6];
  const float* vc_ln_g  = (const float*)d_in[7];
  const float* vc_ln_b  = (const float*)d_in[8];
  const float* vc_alpha = (const float*)d_in[9];
  const float* ec_Wproj = (const float*)d_in[14];
  const float* ec_ln_g  = (const float*)d_in[15];
  const float* ec_ln_b  = (const float*)d_in[16];
  const float* ec_alpha = (const float*)d_in[17];

  float* out = (float*)d_out;
  float* out_node = out;                 // [8,1024,256]
  float* out_edge = out + 2097152;       // [8,1536,256]
  float* out_inc  = out + 5242880;       // [8,1024,1536]

  char* ws = (char*)d_ws;
  float*    PART   = (float*)   (ws + 0);          // 393,216 (8*48*256*4)
  uint16_t* WOUTB  = (uint16_t*)(ws + 4587520);    // 131,072
  uint16_t* WPVB   = (uint16_t*)(ws + 4718592);    // 131,072
  uint16_t* WPEB   = (uint16_t*)(ws + 4849664);    // 131,072
  uint16_t* INCB   = (uint16_t*)(ws + 4988928);    // 25,165,824
  uint16_t* INCT   = (uint16_t*)(ws + 30154752);   // 25,165,824
  uint16_t* QKVB   = (uint16_t*)(ws + 55320576);   // 12,582,912
  uint16_t* SCORESB= (uint16_t*)(ws + 55320576);   // alias: QKVB dead after attn
  uint16_t* OB     = (uint16_t*)(ws + 67903488);   // 4,194,304
  uint16_t* ATTNT  = (uint16_t*)(ws + 72097792);   // 4,194,304
  uint16_t* BASET  = (uint16_t*)(ws + 82583552);   // 6,291,456 (~89 MB total)

  // front launch: qkv GEMM (f32 sources) + fat inc-prep + weight casts
  qkv_prep<<<3648,256,0,stream>>>(inc, out_inc, INCB, INCT,
                                  features, vc_Win, vc_bin, QKVB,
                                  vc_Wout, vc_Wproj, ec_Wproj,
                                  WOUTB, WPVB, WPEB);

  // attention + out-proj (writes ATTNT transposed)
  attn_fwd<<<512,512,0,stream>>>(QKVB, OB);
  gemm_nt<2,128,1><<<dim3(128,2,1),256,0,stream>>>(OB, WOUTB, ATTNT, vc_bout,
                                                   8192,256,256);

  // scores = inc^T @ attn: 32e x 128d tiles, grid 768; VE=v*exp(v) bf16
  // + 48 exp-sum partials per column
  gemm_score<<<768,256,0,stream>>>(INCT, ATTNT, PART, SCORESB);

  // edge path: PART->1/L, p=VE/L staging, GEMM, LN; 16m tiles, grid 768
  gemm_ln_edge<<<768,256,0,stream>>>(SCORESB, WPVB, PART, vc_ln_g, vc_ln_b,
                                     vc_alpha, out_edge, BASET);

  // node path: 16m tiles, grid 512 — W0 = inc@base (K=1536) -> As2 LDS ->
  // @Wpe^T (K=256) + fused LN/blend
  gemm_node_fused<<<512,256,0,stream>>>(INCB, BASET, WPEB, ec_ln_g, ec_ln_b,
                                        ec_alpha, features, out_node);
}

// Round 5
// 241.799 us; speedup vs baseline: 1.3575x; 1.0320x over previous
//
#include <hip/hip_runtime.h>
#include <stdint.h>

// ============================================================================
// MessagePassing collapse:
//   e2 = (3+a_vc)*base,  base = LN((scores*softmax_e(scores)) @ Wp_vc^T)
//   n2 = (1+a)^3 * features + (1-a)((1+a)^2+(1+a)+1) * nb,  a = ec_alpha
//   nb = LN((inc @ base) @ Wp_ec^T)  (LN positive-scale-invariant)
//   EC's MHA is dead code.
// R14: vectorized inc-prep (the only change vs R13). 64x64 tiles: float4
// loads, float4 out_inc stores, u64 incb stores, LDS f32[64][65] transpose
// with 4-lane-contiguous 128B incT runs (uint4 stores). Global instrs/thread
// 64 -> 14. R13 was scalar: 46us @ 3.1TB/s, every pipe idle (issue-bound).
// Predicted ~30us @ ~4.9TB/s. qkv branch, casts, midchain all = R13.
// ============================================================================

#define DEV static __device__ __forceinline__

typedef __attribute__((ext_vector_type(8))) short bf16x8;
typedef __attribute__((ext_vector_type(4))) float f32x4;

DEV uint16_t f2bf(float x){
  union{float f; uint32_t u;} v; v.f=x;
  uint32_t r = v.u + 0x7fffu + ((v.u>>16)&1u);
  return (uint16_t)(r>>16);
}
DEV float bf2f(uint16_t b){
  union{uint32_t u; float f;} v; v.u=((uint32_t)b)<<16; return v.f;
}

DEV uint32_t cvtpk_bf16(float lo, float hi){
  uint32_t d;
  asm("v_cvt_pk_bf16_f32 %0, %1, %2" : "=v"(d) : "v"(lo), "v"(hi));
  return d;
}

#if __has_builtin(__builtin_amdgcn_exp2f)
DEV float exp2fast(float x){ return __builtin_amdgcn_exp2f(x); }
#else
DEV float exp2fast(float x){ return __expf(x * 0.6931471805599453f); }
#endif

#if __has_builtin(__builtin_amdgcn_global_load_lds)
#define HAVE_GLL 1
#else
#define HAVE_GLL 0
#endif

DEV void load_lds16(const uint16_t* g, void* l){
#if HAVE_GLL
  __builtin_amdgcn_global_load_lds((const __attribute__((address_space(1))) uint32_t*)g,
                                   (__attribute__((address_space(3))) uint32_t*)l, 16, 0, 0);
#else
  *(bf16x8*)l = *(const bf16x8*)g;
#endif
}

// ---------------------------------------------------------------------------
// Front launch, 3 block ranges:
//  [0,384):      qkv GEMM C[8192,768] = feats(f32)@Win(f32)^T + bin;
//                tile 128x128, BK=32, reg-staged f32->bf16 (cvt_pk).
//  [384,3456):   inc prep, vectorized: 64rows x 64cols per block
//                (float4 copy out + u64 bf16 + transposed uint4 bf16).
//  [3456,3648):  Wout/Wpv/Wpe f32->bf16 casts (49152 f4 units).
// ---------------------------------------------------------------------------
__global__ __launch_bounds__(256, 3)
void qkv_prep(const float* __restrict__ inc, float* __restrict__ out_inc,
              uint16_t* __restrict__ incb, uint16_t* __restrict__ incT,
              const float* __restrict__ feats, const float* __restrict__ win,
              const float* __restrict__ bias, uint16_t* __restrict__ qkvb,
              const float* __restrict__ wout, const float* __restrict__ wpv,
              const float* __restrict__ wpe,
              uint16_t* __restrict__ ob_w, uint16_t* __restrict__ ov_w,
              uint16_t* __restrict__ oe_w){
  __shared__ union {
    struct { short As[128*32]; short Bs[128*32]; } g;   // 16 KB
    float T[64*65];                                     // 16.6 KB
  } sm;
  const int tid = threadIdx.x;
  const int bx = blockIdx.x;

  if (bx < 384){
    // ---- qkv GEMM, BK=32 ----
    const int lane = tid & 63;
    const int w = tid >> 6;
    const int wm = w & 1, wn = w >> 1;
    const int r = lane & 15, q = lane >> 4;
    const int mtile = bx & 63, ntile = bx >> 6;   // 64 x 6
    const float* Fb = feats + (size_t)(mtile*128)*256;
    const float* Wb = win + (size_t)(ntile*128)*256;
    f32x4 acc[4][4];
#pragma unroll
    for (int i=0;i<4;++i)
#pragma unroll
      for (int j=0;j<4;++j) acc[i][j] = (f32x4){0.f,0.f,0.f,0.f};

    const int srow = tid >> 2;   // 0..63
    const int sblk = tid & 3;    // 0..3 (units of 8 bf16 within BK=32)

    for (int kb = 0; kb < 256; kb += 32){
#pragma unroll
      for (int i=0;i<2;++i){
        int row = srow + 64*i;
        const float* src = Fb + (size_t)row*256 + kb + sblk*8;
        float4 a0 = *(const float4*)src;
        float4 a1 = *(const float4*)(src+4);
        union{uint32_t u[4]; bf16x8 v8;} pk;
        pk.u[0]=cvtpk_bf16(a0.x,a0.y); pk.u[1]=cvtpk_bf16(a0.z,a0.w);
        pk.u[2]=cvtpk_bf16(a1.x,a1.y); pk.u[3]=cvtpk_bf16(a1.z,a1.w);
        *(bf16x8*)&sm.g.As[row*32 + (sblk ^ (row&3))*8] = pk.v8;
      }
#pragma unroll
      for (int i=0;i<2;++i){
        int row = srow + 64*i;
        const float* src = Wb + (size_t)row*256 + kb + sblk*8;
        float4 a0 = *(const float4*)src;
        float4 a1 = *(const float4*)(src+4);
        union{uint32_t u[4]; bf16x8 v8;} pk;
        pk.u[0]=cvtpk_bf16(a0.x,a0.y); pk.u[1]=cvtpk_bf16(a0.z,a0.w);
        pk.u[2]=cvtpk_bf16(a1.x,a1.y); pk.u[3]=cvtpk_bf16(a1.z,a1.w);
        *(bf16x8*)&sm.g.Bs[row*32 + (sblk ^ (row&3))*8] = pk.v8;
      }
      __syncthreads();
      bf16x8 af[4], bfr[4];
#pragma unroll
      for (int mt=0;mt<4;++mt){
        int m = wm*64 + mt*16 + r;
        af[mt] = *(const bf16x8*)&sm.g.As[m*32 + (q ^ (m&3))*8];
      }
#pragma unroll
      for (int nt=0;nt<4;++nt){
        int n = wn*64 + nt*16 + r;
        bfr[nt] = *(const bf16x8*)&sm.g.Bs[n*32 + (q ^ (n&3))*8];
      }
#pragma unroll
      for (int mt=0;mt<4;++mt)
#pragma unroll
        for (int nt=0;nt<4;++nt)
          acc[mt][nt] = __builtin_amdgcn_mfma_f32_16x16x32_bf16(af[mt], bfr[nt], acc[mt][nt], 0,0,0);
      __syncthreads();
    }

    const int gm0 = mtile*128 + wm*64;
    const int gn0 = ntile*128 + wn*64;
#pragma unroll
    for (int mt=0;mt<4;++mt){
#pragma unroll
      for (int nt=0;nt<4;++nt){
        int gn = gn0 + nt*16 + r;
        float bv = bias[gn];
#pragma unroll
        for (int reg=0;reg<4;++reg){
          int gm = gm0 + mt*16 + q*4 + reg;   // C/D: col=lane&15, row=quad*4+reg
          qkvb[(size_t)gm*768 + gn] = f2bf(acc[mt][nt][reg] + bv);
        }
      }
    }
  } else if (bx < 3456){
    // ---- inc prep, vectorized 64x64 tile ----
    int p = bx - 384;
    int x = p % 24;             // 64-col tile (1536/64)
    int t = p / 24;
    int y = t & 15;             // 64-row tile (1024/64)
    int b = t >> 4;             // batch
    int c0 = x*64, r0 = y*64;
    int tx = tid & 15, ty = tid >> 4;   // 16 x 16
    size_t base = (size_t)b*1024*1536;
#pragma unroll
    for (int jj=0;jj<4;++jj){
      int rl = ty + jj*16;
      size_t idx = base + (size_t)(r0+rl)*1536 + c0 + tx*4;
      float4 v = *(const float4*)&inc[idx];
      *(float4*)&out_inc[idx] = v;
      union{uint16_t u[4]; uint64_t q64;} pk;
      pk.u[0]=f2bf(v.x); pk.u[1]=f2bf(v.y); pk.u[2]=f2bf(v.z); pk.u[3]=f2bf(v.w);
      *(uint64_t*)&incb[idx] = pk.q64;
      float* Tp = &sm.T[rl*65 + tx*4];
      Tp[0]=v.x; Tp[1]=v.y; Tp[2]=v.z; Tp[3]=v.w;
    }
    __syncthreads();
    // transposed write: c = tid>>2 (0..63 e-rows), ms = (tid&3)*16 m-offset;
    // lanes 0-3 cover one row's 128B contiguously.
    int c = tid >> 2, ms = (tid & 3) * 16;
    size_t baseT = (size_t)b*1536*1024;
    uint16_t* dst = incT + baseT + (size_t)(c0+c)*1024 + r0 + ms;
    union{uint16_t u[8]; uint4 v4;} o0, o1;
#pragma unroll
    for (int j=0;j<8;++j) o0.u[j] = f2bf(sm.T[(ms+j)*65 + c]);
#pragma unroll
    for (int j=0;j<8;++j) o1.u[j] = f2bf(sm.T[(ms+8+j)*65 + c]);
    *(uint4*)dst = o0.v4;
    *(uint4*)(dst+8) = o1.v4;
  } else {
    // ---- weight casts: Wout/Wpv/Wpe, 16384 f4-units each ----
    int i = (bx - 3456)*256 + tid;
    const float* src; uint16_t* dst; int j;
    if (i < 16384){ src=wout; dst=ob_w; j=i; }
    else if (i < 32768){ src=wpv; dst=ov_w; j=i-16384; }
    else { src=wpe; dst=oe_w; j=i-32768; }
    float4 v = ((const float4*)src)[j];
    union { uint16_t u[4]; uint64_t q; } p;
    p.u[0]=f2bf(v.x); p.u[1]=f2bf(v.y); p.u[2]=f2bf(v.z); p.u[3]=f2bf(v.w);
    ((uint64_t*)dst)[j] = p.q;
  }
}

// ---------------------------------------------------------------------------
// NT bf16 GEMM (LDS-staged): C[M,N] = A[M,K]*B[N,K]^T (+bias).
// EPI 1 = transposed bf16 store (per-batch [N][1024]). Used for outproj.
// ---------------------------------------------------------------------------
template<int WM, int BK, int EPI>
__global__ __launch_bounds__(256, 3)
void gemm_nt(const uint16_t* __restrict__ A, const uint16_t* __restrict__ B,
             uint16_t* __restrict__ Cb, const float* __restrict__ bias,
             int M, int N, int K){
  constexpr int AROWS = WM*32;
  constexpr int UPR = BK/8;
  constexpr int RPP = 256/UPR;
  __shared__ short As[AROWS*BK];
  __shared__ short Bs[128*BK];
  const int tid = threadIdx.x;
  const int lane = tid & 63;
  const int w = tid >> 6;
  const int wm = w & 1, wn = w >> 1;
  const int r = lane & 15, q = lane >> 4;
  const uint16_t* Ab = A + (size_t)(blockIdx.x*AROWS)*K;
  const uint16_t* Bb = B + (size_t)(blockIdx.y*128)*K;
  f32x4 acc[WM][4];
#pragma unroll
  for (int i=0;i<WM;++i)
#pragma unroll
    for (int j=0;j<4;++j) acc[i][j] = (f32x4){0.f,0.f,0.f,0.f};

  const int srow = tid / UPR;
  const int sblk = tid % UPR;

  for (int kb = 0; kb < K; kb += BK){
#pragma unroll
    for (int i=0;i<AROWS/RPP;++i){
      int row = srow + RPP*i;
      int lblk = sblk ^ (row & (UPR-1));
      load_lds16(Ab + (size_t)row*K + kb + lblk*8, (char*)As + i*4096 + tid*16);
    }
#pragma unroll
    for (int i=0;i<128/RPP;++i){
      int row = srow + RPP*i;
      int lblk = sblk ^ (row & (UPR-1));
      load_lds16(Bb + (size_t)row*K + kb + lblk*8, (char*)Bs + i*4096 + tid*16);
    }
    __syncthreads();
#pragma unroll
    for (int kc=0;kc<BK/32;++kc){
      bf16x8 af[WM], bfr[4];
#pragma unroll
      for (int mt=0;mt<WM;++mt){
        int m = wm*(WM*16) + mt*16 + r;
        af[mt] = *(const bf16x8*)&As[m*BK + ((kc*4 + q) ^ (m&(UPR-1)))*8];
      }
#pragma unroll
      for (int nt=0;nt<4;++nt){
        int n = wn*64 + nt*16 + r;
        bfr[nt] = *(const bf16x8*)&Bs[n*BK + ((kc*4 + q) ^ (n&(UPR-1)))*8];
      }
#pragma unroll
      for (int mt=0;mt<WM;++mt)
#pragma unroll
        for (int nt=0;nt<4;++nt)
          acc[mt][nt] = __builtin_amdgcn_mfma_f32_16x16x32_bf16(af[mt], bfr[nt], acc[mt][nt], 0,0,0);
    }
    __syncthreads();
  }

  const int gm0 = blockIdx.x*AROWS + wm*(WM*16);
  const int gn0 = blockIdx.y*128 + wn*64;

  if constexpr (EPI == 1){
#pragma unroll
    for (int mt=0;mt<WM;++mt){
      int gmb = gm0 + mt*16 + q*4;
      size_t bb_ = (size_t)(gmb>>10)*(256*1024);
      int mm = gmb & 1023;
#pragma unroll
      for (int nt=0;nt<4;++nt){
        int gn = gn0 + nt*16 + r;
        float bv = bias ? bias[gn] : 0.f;
        union{uint16_t u[4]; uint64_t q64;} pk;
#pragma unroll
        for (int reg=0;reg<4;++reg) pk.u[reg] = f2bf(acc[mt][nt][reg] + bv);
        *(uint64_t*)(Cb + bb_ + (size_t)gn*1024 + mm) = pk.q64;
      }
    }
  } else {
#pragma unroll
    for (int mt=0;mt<WM;++mt){
#pragma unroll
      for (int nt=0;nt<4;++nt){
        int gn = gn0 + nt*16 + r;
        float bv = bias ? bias[gn] : 0.f;
#pragma unroll
        for (int reg=0;reg<4;++reg){
          int gm = gm0 + mt*16 + q*4 + reg;
          Cb[(size_t)gm*N + gn] = f2bf(acc[mt][nt][reg] + bv);
        }
      }
    }
  }
}

// ---------------------------------------------------------------------------
// scores GEMM: C[e,d] = incT[e,:].attnT[d,:] (K=1024). Tile 32e x 128d,
// 4 waves x 32 cols. Grid 768 = 8 batches * 48 etiles * 2 dhalves,
// XCD-swizzled. Writes VE=v*exp(v) bf16 + column exp-sum partials
// (48 partials per column, layout part[batch][48][256]).
// ---------------------------------------------------------------------------
__global__ __launch_bounds__(256, 4)
void gemm_score(const uint16_t* __restrict__ A,   // INCT flat [8*1536][1024]
                const uint16_t* __restrict__ B,   // ATTNT [8][256][1024]
                float* __restrict__ part,         // [8][48][256]
                uint16_t* __restrict__ VE){       // [8*1536][256]
  __shared__ short As[32*64];     // 4 KB
  __shared__ short Bs[128*64];    // 16 KB
  const int tid = threadIdx.x;
  const int lane = tid & 63;
  const int w = tid >> 6;
  const int r = lane & 15, q = lane >> 4;
  const int bx = (blockIdx.x & 7)*96 + (blockIdx.x >> 3);   // bijective, 768=8*96
  const int batch = bx / 96;
  const int t = bx % 96;
  const int etile = t >> 1, dh = t & 1;
  const uint16_t* Ab = A + (size_t)(batch*1536 + etile*32)*1024;
  const uint16_t* Bb = B + (size_t)(batch*256 + dh*128)*1024;

  f32x4 acc[2][2];
#pragma unroll
  for (int i=0;i<2;++i)
#pragma unroll
    for (int j=0;j<2;++j) acc[i][j] = (f32x4){0.f,0.f,0.f,0.f};

  const int srow = tid >> 3;   // 0..31
  const int sblk = tid & 7;

  for (int kb = 0; kb < 1024; kb += 64){
    { int lblk = sblk ^ (srow & 7);
      load_lds16(Ab + (size_t)srow*1024 + kb + lblk*8, (char*)As + tid*16); }
#pragma unroll
    for (int i=0;i<4;++i){
      int row = srow + 32*i;
      int lblk = sblk ^ (row & 7);
      load_lds16(Bb + (size_t)row*1024 + kb + lblk*8, (char*)Bs + i*4096 + tid*16);
    }
    __syncthreads();
#pragma unroll
    for (int kc=0;kc<2;++kc){
      bf16x8 af[2], bfr[2];
#pragma unroll
      for (int mt=0;mt<2;++mt){
        int m = mt*16 + r;
        af[mt] = *(const bf16x8*)&As[m*64 + ((kc*4 + q) ^ (m&7))*8];
      }
#pragma unroll
      for (int nt=0;nt<2;++nt){
        int n = w*32 + nt*16 + r;
        bfr[nt] = *(const bf16x8*)&Bs[n*64 + ((kc*4 + q) ^ (n&7))*8];
      }
#pragma unroll
      for (int mt=0;mt<2;++mt)
#pragma unroll
        for (int nt=0;nt<2;++nt)
          acc[mt][nt] = __builtin_amdgcn_mfma_f32_16x16x32_bf16(af[mt], bfr[nt], acc[mt][nt], 0,0,0);
    }
    __syncthreads();
  }

  const size_t er0 = (size_t)batch*1536 + etile*32;
#pragma unroll
  for (int nt=0;nt<2;++nt){
    int gn = dh*128 + w*32 + nt*16 + r;
    float s = 0.f;
#pragma unroll
    for (int mt=0;mt<2;++mt){
#pragma unroll
      for (int reg=0;reg<4;++reg){
        float v = acc[mt][nt][reg];
        float ev = __expf(v);
        s += ev;
        int row = mt*16 + q*4 + reg;
        VE[(er0 + row)*256 + gn] = f2bf(v*ev);
      }
    }
    s += __shfl_xor(s, 16);
    s += __shfl_xor(s, 32);
    if (q == 0) part[(size_t)(batch*48 + etile)*256 + gn] = s;
  }
}

// ---------------------------------------------------------------------------
// Edge path: A = VE * (1/L) staged (cvt_pk), L folded from 48 partials.
// Tile 16m x 256n (LN over full 256 in-block), grid 768 = 8*96, XCD-swizzled.
// Writes out_edge f32 + BASET bf16 [b][d][e].
// ---------------------------------------------------------------------------
__global__ __launch_bounds__(256, 4)
void gemm_ln_edge(const uint16_t* __restrict__ SB, const uint16_t* __restrict__ B,
                  const float* __restrict__ part, const float* __restrict__ g,
                  const float* __restrict__ bb, const float* __restrict__ alpha,
                  float* __restrict__ out, uint16_t* __restrict__ baset){
  __shared__ short As[16*64];     // 2 KB
  __shared__ short Bs[256*64];    // 32 KB
  __shared__ float lnS[4][16], lnQ[4][16];
  __shared__ float PLinv[256];
  const int tid = threadIdx.x;
  const int lane = tid & 63;
  const int w = tid >> 6;          // wave = d-strip 0..3
  const int r = lane & 15, q = lane >> 4;
  const int bx = (blockIdx.x & 7)*96 + (blockIdx.x >> 3);   // 768=8*96
  const int batch = bx / 96;

  {
    float s = 0.f;
#pragma unroll
    for (int i=0;i<48;++i) s += part[((size_t)batch*48 + i)*256 + tid];
    PLinv[tid] = 1.0f / s;
  }
  __syncthreads();

  f32x4 acc[4];
#pragma unroll
  for (int j=0;j<4;++j) acc[j] = (f32x4){0.f,0.f,0.f,0.f};

  const int srow = tid >> 3;   // 0..31 (A uses 0..15 via tid<128)
  const int sblk = tid & 7;

  for (int kb = 0; kb < 256; kb += 64){
    if (tid < 128){
      bf16x8 v = *(const bf16x8*)(SB + (size_t)(bx*16 + srow)*256 + kb + sblk*8);
      const float* Lp = &PLinv[kb + sblk*8];
      float xv[8];
#pragma unroll
      for (int j=0;j<8;++j) xv[j] = bf2f((uint16_t)v[j]) * Lp[j];
      union{uint32_t u[4]; bf16x8 v8;} pk;
      pk.u[0] = cvtpk_bf16(xv[0], xv[1]);
      pk.u[1] = cvtpk_bf16(xv[2], xv[3]);
      pk.u[2] = cvtpk_bf16(xv[4], xv[5]);
      pk.u[3] = cvtpk_bf16(xv[6], xv[7]);
      *(bf16x8*)&As[srow*64 + (sblk ^ (srow&7))*8] = pk.v8;
    }
#pragma unroll
    for (int i=0;i<8;++i){
      int row = srow + 32*i;
      int lblk = sblk ^ (row & 7);
      load_lds16(B + (size_t)row*256 + kb + lblk*8, (char*)Bs + i*4096 + tid*16);
    }
    __syncthreads();
#pragma unroll
    for (int kc=0;kc<2;++kc){
      bf16x8 af, bfr[4];
      { int m = r;
        af = *(const bf16x8*)&As[m*64 + ((kc*4 + q) ^ (m&7))*8]; }
#pragma unroll
      for (int nt=0;nt<4;++nt){
        int n = w*64 + nt*16 + r;
        bfr[nt] = *(const bf16x8*)&Bs[n*64 + ((kc*4 + q) ^ (n&7))*8];
      }
#pragma unroll
      for (int nt=0;nt<4;++nt)
        acc[nt] = __builtin_amdgcn_mfma_f32_16x16x32_bf16(af, bfr[nt], acc[nt], 0,0,0);
    }
    __syncthreads();
  }

  // cross-wave LN reduction (rows = q*4+reg, 16 rows)
  float rs[4], rq[4];
#pragma unroll
  for (int reg=0;reg<4;++reg){
    float s=0.f, s2=0.f;
#pragma unroll
    for (int nt=0;nt<4;++nt){
      float v = acc[nt][reg];
      s += v; s2 += v*v;
    }
#pragma unroll
    for (int off=1; off<16; off<<=1){ s += __shfl_xor(s,off); s2 += __shfl_xor(s2,off); }
    rs[reg]=s; rq[reg]=s2;
  }
  if (r == 0){
#pragma unroll
    for (int reg=0;reg<4;++reg){
      int row = q*4 + reg;
      lnS[w][row] = rs[reg];
      lnQ[w][row] = rq[reg];
    }
  }
  __syncthreads();

  const float c0 = 3.0f + alpha[0];
  float mu_[4], rstd_[4];
#pragma unroll
  for (int reg=0;reg<4;++reg){
    int row = q*4 + reg;
    float S = lnS[0][row]+lnS[1][row]+lnS[2][row]+lnS[3][row];
    float Q = lnQ[0][row]+lnQ[1][row]+lnQ[2][row]+lnQ[3][row];
    float mu = S * (1.f/256.f);
    float var = fmaxf(Q*(1.f/256.f) - mu*mu, 0.f);
    mu_[reg] = mu;
    rstd_[reg] = rsqrtf(var + 1e-5f);
  }

  int e0 = (bx % 96) * 16;
#pragma unroll
  for (int nt=0;nt<4;++nt){
    int gn = w*64 + nt*16 + r;
    float gv = g[gn], bv = bb[gn];
    union{uint16_t u[4]; uint64_t q64;} pk;
#pragma unroll
    for (int reg=0;reg<4;++reg){
      int row = q*4 + reg;
      size_t gm = (size_t)bx*16 + row;
      float o = ((acc[nt][reg]-mu_[reg])*rstd_[reg]*gv + bv) * c0;
      pk.u[reg] = f2bf(o);
      out[gm*256 + gn] = o;
    }
    int ee = e0 + q*4;
    *(uint64_t*)(baset + ((size_t)batch*256 + gn)*1536 + ee) = pk.q64;
  }
}

// ---------------------------------------------------------------------------
// Fused node path: 16m x 256d tiles, grid 512 = 8 batches * 64 m-tiles,
// XCD-swizzled.
//   phase 1: W0^T[d,m] = BASET[d,:].INCB[m,:] (K=1536) -> As2 bf16 swz
//   phase 2: C2^T[d',m] = WPEB[d',:].As2[m,:] (K=256)
//   epilogue: per-m LN over d' + blend with features.
// ---------------------------------------------------------------------------
__global__ __launch_bounds__(256, 3)
void gemm_node_fused(const uint16_t* __restrict__ inc,    // INCB [8][1024][1536]
                     const uint16_t* __restrict__ baset,  // [8][256][1536]
                     const uint16_t* __restrict__ wpe,    // [256][256]
                     const float* __restrict__ g, const float* __restrict__ bb,
                     const float* __restrict__ alpha,
                     const float* __restrict__ feats, float* __restrict__ out){
  __shared__ short Ws[256*64];    // 32KB
  __shared__ short As2[16*256];   // 8KB: W0 bf16, swizzled
  __shared__ short Is[16*64];     // 2KB: inc chunk; aliased lnS/lnQ later
  const int tid = threadIdx.x;
  const int lane = tid & 63;
  const int w = tid >> 6;
  const int r = lane & 15, q = lane >> 4;
  const int bx = (blockIdx.x & 7)*64 + (blockIdx.x >> 3);  // bijective, 512=8*64
  const int batch = bx >> 6;
  const int mt0 = (bx & 63) * 16;

  const int srow = tid >> 3;   // 0..31
  const int sblk = tid & 7;

  const uint16_t* Bb = baset + (size_t)batch*256*1536;
  const uint16_t* Ib = inc + ((size_t)batch*1024 + mt0)*1536;

  f32x4 acc1[4];
#pragma unroll
  for (int i=0;i<4;++i) acc1[i] = (f32x4){0.f,0.f,0.f,0.f};

  // ---- phase 1: K=1536 ----
  for (int kb = 0; kb < 1536; kb += 64){
#pragma unroll
    for (int i=0;i<8;++i){
      int row = srow + 32*i;
      int lblk = sblk ^ (row & 7);
      load_lds16(Bb + (size_t)row*1536 + kb + lblk*8, (char*)Ws + i*4096 + tid*16);
    }
    if (tid < 128){
      int lblk = sblk ^ (srow & 7);
      load_lds16(Ib + (size_t)srow*1536 + kb + lblk*8, (char*)Is + tid*16);
    }
    __syncthreads();
#pragma unroll
    for (int kc=0;kc<2;++kc){
      bf16x8 af[4], bfr;
#pragma unroll
      for (int mt=0;mt<4;++mt){
        int d = w*64 + mt*16 + r;
        af[mt] = *(const bf16x8*)&Ws[d*64 + ((kc*4 + q) ^ (d&7))*8];
      }
      { int m = r;
        bfr = *(const bf16x8*)&Is[m*64 + ((kc*4 + q) ^ (m&7))*8]; }
#pragma unroll
      for (int mt=0;mt<4;++mt)
        acc1[mt] = __builtin_amdgcn_mfma_f32_16x16x32_bf16(af[mt], bfr, acc1[mt], 0,0,0);
    }
    __syncthreads();
  }

  // ---- W0^T -> As2[m][d] bf16, 16B-unit XOR swizzle (j ^ (m&7)) ----
  // acc1[mt][reg] = W0^T[d][m], d = w*64+mt*16+q*4+reg, m = r.
#pragma unroll
  for (int mt=0;mt<4;++mt){
    int j = w*8 + mt*2 + (q>>1);
    int m = r;
    union{uint16_t u[4]; uint64_t q64;} pk;
#pragma unroll
    for (int reg=0;reg<4;++reg) pk.u[reg] = f2bf(acc1[mt][reg]);
    *(uint64_t*)((char*)As2 + m*512 + ((j ^ (m&7))<<4) + ((q&1)<<3)) = pk.q64;
  }

  // ---- phase 2: K=256, A = WPEB, B = As2 ----
  f32x4 acc2[4];
#pragma unroll
  for (int i=0;i<4;++i) acc2[i] = (f32x4){0.f,0.f,0.f,0.f};

  for (int kb = 0; kb < 256; kb += 64){
#pragma unroll
    for (int i=0;i<8;++i){
      int row = srow + 32*i;
      int lblk = sblk ^ (row & 7);
      load_lds16(wpe + (size_t)row*256 + kb + lblk*8, (char*)Ws + i*4096 + tid*16);
    }
    __syncthreads();   // orders As2 writes + Ws restage before reads
#pragma unroll
    for (int kc=0;kc<2;++kc){
      bf16x8 af[4], bfr;
#pragma unroll
      for (int mt=0;mt<4;++mt){
        int dp = w*64 + mt*16 + r;
        af[mt] = *(const bf16x8*)&Ws[dp*64 + ((kc*4 + q) ^ (dp&7))*8];
      }
      { int m = r;
        int jr = (kb>>3) + kc*4 + q;
        bfr = *(const bf16x8*)((char*)As2 + m*512 + ((jr ^ (m&7))<<4)); }
#pragma unroll
      for (int mt=0;mt<4;++mt)
        acc2[mt] = __builtin_amdgcn_mfma_f32_16x16x32_bf16(af[mt], bfr, acc2[mt], 0,0,0);
    }
    __syncthreads();
  }

  // ---- LN over d' (per column m = r), cross-wave via LDS (alias Is) ----
  float* lnS = (float*)Is;        // [4][16]
  float* lnQ = lnS + 64;          // [4][16]
  float s_, q_;
  {
    float s=0.f, s2=0.f;
#pragma unroll
    for (int mt=0;mt<4;++mt)
#pragma unroll
      for (int reg=0;reg<4;++reg){
        float v = acc2[mt][reg];
        s += v; s2 += v*v;
      }
    s += __shfl_xor(s,16); s2 += __shfl_xor(s2,16);
    s += __shfl_xor(s,32); s2 += __shfl_xor(s2,32);
    s_ = s; q_ = s2;
  }
  if (q == 0){
    lnS[w*16 + r] = s_;
    lnQ[w*16 + r] = q_;
  }
  __syncthreads();

  const float a = alpha[0];
  const float ap1 = 1.f + a;
  const float cn = (1.f - a)*(ap1*ap1 + ap1 + 1.f);
  const float cf = ap1*ap1*ap1;

  float mu_, rstd_;
  {
    int col = r;
    float S = lnS[col] + lnS[16+col] + lnS[32+col] + lnS[48+col];
    float Q = lnQ[col] + lnQ[16+col] + lnQ[32+col] + lnQ[48+col];
    float mu = S * (1.f/256.f);
    float var = fmaxf(Q*(1.f/256.f) - mu*mu, 0.f);
    mu_ = mu;
    rstd_ = rsqrtf(var + 1e-5f);
  }

  // ---- epilogue: out[m][d'] = cf*feats + cn*LN ----
#pragma unroll
  for (int mt=0;mt<4;++mt){
    int dp0 = w*64 + mt*16 + q*4;
    float4 gv = *(const float4*)&g[dp0];
    float4 bv = *(const float4*)&bb[dp0];
    int m = r;
    size_t gm = (size_t)batch*1024 + mt0 + m;
    float4 fv = *(const float4*)&feats[gm*256 + dp0];
    float4 ov;
    ov.x = cf*fv.x + cn*((acc2[mt][0]-mu_)*rstd_*gv.x + bv.x);
    ov.y = cf*fv.y + cn*((acc2[mt][1]-mu_)*rstd_*gv.y + bv.y);
    ov.z = cf*fv.z + cn*((acc2[mt][2]-mu_)*rstd_*gv.z + bv.z);
    ov.w = cf*fv.w + cn*((acc2[mt][3]-mu_)*rstd_*gv.w + bv.w);
    *(float4*)&out[gm*256 + dp0] = ov;
  }
}

// ---------------------------------------------------------------------------
// Attention (unchanged): S^T = K*Q^T, packed b64 P-store, scalar l.
// 512 thr = 8 waves x 16 q-rows. grid 512 (1D, XCD-swizzled). Max-free
// softmax; exp2 direct; cvt_pk P-pack; setprio around MFMA (T5).
// ---------------------------------------------------------------------------
DEV void stage_K(short* Kl, const uint16_t* __restrict__ qkv, size_t rowbase,
                 int c, int h, int kr){
  const uint16_t* kp = qkv + ((rowbase + c*256 + kr)*768 + 256 + h*32);
  int sz = (kr&3) ^ ((kr>>2)&1);
#pragma unroll
  for (int lb=0; lb<4; ++lb){
    bf16x8 v = *(const bf16x8*)(kp + lb*8);
    *(bf16x8*)&Kl[kr*32 + ((lb ^ sz))*8] = v;
  }
}

DEV void stage_V(short* VT, const uint16_t* __restrict__ qkv, size_t rowbase,
                 int c, int h, int t){
  int kvp = (t>>1)*2;
  int dhh = (t&1)*16;
  const uint16_t* v0 = qkv + ((rowbase + c*256 + kvp)*768 + 512 + h*32 + dhh);
  const uint16_t* v1 = v0 + 768;
  bf16x8 a0 = *(const bf16x8*)(v0);
  bf16x8 a1 = *(const bf16x8*)(v0+8);
  bf16x8 b0 = *(const bf16x8*)(v1);
  bf16x8 b1 = *(const bf16x8*)(v1+8);
  int blkbase = kvp>>3, off = kvp&7;
#pragma unroll
  for (int i=0;i<8;++i){
    int dh = dhh + i;
    uint32_t pack = (uint32_t)(uint16_t)a0[i] | ((uint32_t)(uint16_t)b0[i]<<16);
    *(uint32_t*)&VT[dh*256 + ((blkbase ^ (dh&7))*8) + off] = pack;
  }
#pragma unroll
  for (int i=0;i<8;++i){
    int dh = dhh + 8 + i;
    uint32_t pack = (uint32_t)(uint16_t)a1[i] | ((uint32_t)(uint16_t)b1[i]<<16);
    *(uint32_t*)&VT[dh*256 + ((blkbase ^ (dh&7))*8) + off] = pack;
  }
}

__global__ __launch_bounds__(512)
void attn_fwd(const uint16_t* __restrict__ qkv, uint16_t* __restrict__ O){
  __shared__ short Kl[256*32];
  __shared__ short VT[32*256];
  __shared__ short Pl[8][16*36];
  const int tid = threadIdx.x, lane = tid&63, w = tid>>6;
  const int r = lane&15, q = lane>>4;
  const int logical = (blockIdx.x & 7)*64 + (blockIdx.x >> 3); // 512=8*64 bijective
  const int bh = logical >> 3, qc = logical & 7;
  const int b = bh>>3, h = bh&7;
  const int q0 = qc*128 + w*16;
  const size_t rowbase = (size_t)b*1024;

  bf16x8 aq;
  {
    // 1/sqrt(32) * log2(e): p = exp2(S_mfma)
    const float qscale = 0.25505654380651023f;
    const uint16_t* p = qkv + ((rowbase + q0 + r)*768 + h*32 + q*8);
    bf16x8 t = *(const bf16x8*)p;
#pragma unroll
    for (int j=0;j<8;++j)
      t[j] = (short)f2bf(bf2f((uint16_t)t[j]) * qscale);
    aq = t;
  }

  f32x4 o[2];
  o[0]=(f32x4){0.f,0.f,0.f,0.f}; o[1]=(f32x4){0.f,0.f,0.f,0.f};
  float l = 0.f;

  for (int c=0;c<4;++c){
    __syncthreads();
    if (tid < 256) stage_K(Kl, qkv, rowbase, c, h, tid);
    else           stage_V(VT, qkv, rowbase, c, h, tid-256);
    __syncthreads();
    for (int s32=0; s32<8; ++s32){
#pragma unroll
      for (int t2=0;t2<2;++t2){
        int rn = s32*32 + t2*16 + r;
        int sz = (rn&3) ^ ((rn>>2)&1);
        bf16x8 bk = *(const bf16x8*)&Kl[rn*32 + ((q ^ sz))*8];
        f32x4 z = (f32x4){0.f,0.f,0.f,0.f};
        __builtin_amdgcn_s_setprio(1);
        f32x4 st = __builtin_amdgcn_mfma_f32_16x16x32_bf16(bk, aq, z, 0,0,0);
        __builtin_amdgcn_s_setprio(0);
        float p0 = exp2fast(st[0]);
        float p1 = exp2fast(st[1]);
        float p2 = exp2fast(st[2]);
        float p3 = exp2fast(st[3]);
        l += (p0+p1)+(p2+p3);
        union{uint32_t u[2]; uint64_t q64;} pk;
        pk.u[0] = cvtpk_bf16(p0, p1);
        pk.u[1] = cvtpk_bf16(p2, p3);
        *(uint64_t*)&Pl[w][r*36 + t2*16 + q*4] = pk.q64;
      }
      bf16x8 bv[2];
#pragma unroll
      for (int db=0;db<2;++db){
        int dh = db*16 + r;
        bv[db] = *(const bf16x8*)&VT[dh*256 + (((s32*4 + q) ^ (dh&7)))*8];
      }
      bf16x8 ap = *(const bf16x8*)&Pl[w][r*36 + q*8];
      __builtin_amdgcn_s_setprio(1);
#pragma unroll
      for (int db=0;db<2;++db)
        o[db] = __builtin_amdgcn_mfma_f32_16x16x32_bf16(ap, bv[db], o[db], 0,0,0);
      __builtin_amdgcn_s_setprio(0);
    }
  }

  l += __shfl_xor(l, 16);
  l += __shfl_xor(l, 32);
#pragma unroll
  for (int db=0;db<2;++db)
#pragma unroll
    for (int reg=0;reg<4;++reg){
      float li = __shfl(l, q*4 + reg);
      int qr = q0 + q*4 + reg;
      O[(rowbase + qr)*256 + h*32 + db*16 + r] = f2bf(o[db][reg] / li);
    }
}

// ===========================================================================
extern "C" void kernel_launch(void* const* d_in, const int* in_sizes, int n_in,
                              void* d_out, int out_size, void* d_ws, size_t ws_size,
                              hipStream_t stream){
  const float* features = (const float*)d_in[0];
  const float* inc      = (const float*)d_in[1];
  const float* vc_Win   = (const float*)d_in[2];
  const float* vc_bin   = (const float*)d_in[3];
  const float* vc_Wout  = (const float*)d_in[4];
  const float* vc_bout  = (const float*)d_in[5];
  const float* vc_Wproj = (const float*)d_in[6];
  const float* vc_ln_g  = (const float*)d_in[7];
  const float* vc_ln_b  = (const float*)d_in[8];
  const float* vc_alpha = (const float*)d_in[9];
  const float* ec_Wproj = (const float*)d_in[14];
  const float* ec_ln_g  = (const float*)d_in[15];
  const float* ec_ln_b  = (const float*)d_in[16];
  const float* ec_alpha = (const float*)d_in[17];

  float* out = (float*)d_out;
  float* out_node = out;                 // [8,1024,256]
  float* out_edge = out + 2097152;       // [8,1536,256]
  float* out_inc  = out + 5242880;       // [8,1024,1536]

  char* ws = (char*)d_ws;
  float*    PART   = (float*)   (ws + 0);          // 393,216 (8*48*256*4)
  uint16_t* WOUTB  = (uint16_t*)(ws + 4587520);    // 131,072
  uint16_t* WPVB   = (uint16_t*)(ws + 4718592);    // 131,072
  uint16_t* WPEB   = (uint16_t*)(ws + 4849664);    // 131,072
  uint16_t* INCB   = (uint16_t*)(ws + 4988928);    // 25,165,824
  uint16_t* INCT   = (uint16_t*)(ws + 30154752);   // 25,165,824
  uint16_t* QKVB   = (uint16_t*)(ws + 55320576);   // 12,582,912
  uint16_t* SCORESB= (uint16_t*)(ws + 55320576);   // alias: QKVB dead after attn
  uint16_t* OB     = (uint16_t*)(ws + 67903488);   // 4,194,304
  uint16_t* ATTNT  = (uint16_t*)(ws + 72097792);   // 4,194,304
  uint16_t* BASET  = (uint16_t*)(ws + 82583552);   // 6,291,456 (~89 MB total)

  // front launch: qkv GEMM (f32 sources) + vectorized inc-prep + weight casts
  qkv_prep<<<3648,256,0,stream>>>(inc, out_inc, INCB, INCT,
                                  features, vc_Win, vc_bin, QKVB,
                                  vc_Wout, vc_Wproj, ec_Wproj,
                                  WOUTB, WPVB, WPEB);

  // attention + out-proj (writes ATTNT transposed)
  attn_fwd<<<512,512,0,stream>>>(QKVB, OB);
  gemm_nt<2,128,1><<<dim3(128,2,1),256,0,stream>>>(OB, WOUTB, ATTNT, vc_bout,
                                                   8192,256,256);

  // scores = inc^T @ attn: 32e x 128d tiles, grid 768; VE=v*exp(v) bf16
  // + 48 exp-sum partials per column
  gemm_score<<<768,256,0,stream>>>(INCT, ATTNT, PART, SCORESB);

  // edge path: PART->1/L, p=VE/L staging, GEMM, LN; 16m tiles, grid 768
  gemm_ln_edge<<<768,256,0,stream>>>(SCORESB, WPVB, PART, vc_ln_g, vc_ln_b,
                                     vc_alpha, out_edge, BASET);

  // node path: 16m tiles, grid 512 — W0 = inc@base (K=1536) -> As2 LDS ->
  // @Wpe^T (K=256) + fused LN/blend
  gemm_node_fused<<<512,256,0,stream>>>(INCB, BASET, WPEB, ec_ln_g, ec_ln_b,
                                        ec_alpha, features, out_node);
}